// Round 12
// baseline (138.244 us; speedup 1.0000x reference)
//
#include <hip/hip_runtime.h>

// Problem constants
#define PB 2
#define PS 2048
#define PHID 1024
#define PH 16
#define PKV 8
#define PD 64
#define PM (PB*PS)    // 4096
#define PR (PB*PH*PS) // 65536 q-rows total

typedef _Float16 f16_t;
typedef _Float16 f16x8 __attribute__((ext_vector_type(8)));
typedef _Float16 f16x2 __attribute__((ext_vector_type(2)));
typedef __fp16 fp16v2 __attribute__((ext_vector_type(2)));   // cvt_pkrtz native type
typedef float f32x4 __attribute__((ext_vector_type(4)));

#define MFMAH(a,b,c)  __builtin_amdgcn_mfma_f32_16x16x32_f16((a),(b),(c),0,0,0)
#define LOG2E 1.44269504f

// global -> LDS direct copy, 16B per lane (dst = uniform base + lane*16).
__device__ __forceinline__ void gl16(const f16_t* g, f16_t* l) {
  __builtin_amdgcn_global_load_lds(
      (const __attribute__((address_space(1))) void*)g,
      (__attribute__((address_space(3))) void*)l, 16, 0, 0);
}

// ---------------------------------------------------------------------------
// Kernel 0a: hs fp32 -> fp16.
// ---------------------------------------------------------------------------
__global__ __launch_bounds__(256)
void convert_hs(const float* __restrict__ hs, f16_t* __restrict__ hf)
{
  const size_t i = ((size_t)blockIdx.x * 256 + threadIdx.x) * 8;
  float4 a = *(const float4*)&hs[i];
  float4 b = *(const float4*)&hs[i + 4];
  float xs[8] = {a.x, a.y, a.z, a.w, b.x, b.y, b.z, b.w};
  f16x8 v;
  #pragma unroll
  for (int j = 0; j < 8; ++j) v[j] = (f16_t)xs[j];
  *(f16x8*)&hf[i] = v;
}

// ---------------------------------------------------------------------------
// Kernel 0b: weights -> transposed [n][k] fp16 (rows: Wq^T 0-1023, Wk^T
// 1024-1535, Wv^T 1536-2047, Wo^T 2048-3071). grid 768.
// ---------------------------------------------------------------------------
__global__ __launch_bounds__(256)
void convert_w(const float* __restrict__ Wq, const float* __restrict__ Wk,
               const float* __restrict__ Wv, const float* __restrict__ Wo,
               f16_t* __restrict__ wtT)
{
  __shared__ float Tt[64][68];
  const int tid = threadIdx.x;
  const int slot = blockIdx.x >> 4, k0 = (blockIdx.x & 15) * 64;

  const float* src; int N, ncol0, orow0;
  if (slot < 16)      { src = Wq; N = 1024; ncol0 = slot*64;      orow0 = slot*64; }
  else if (slot < 24) { src = Wk; N = 512;  ncol0 = (slot-16)*64; orow0 = 1024 + (slot-16)*64; }
  else if (slot < 32) { src = Wv; N = 512;  ncol0 = (slot-24)*64; orow0 = 1536 + (slot-24)*64; }
  else                { src = Wo; N = 1024; ncol0 = (slot-32)*64; orow0 = 2048 + (slot-32)*64; }

  const int tk = tid >> 6, tn = tid & 63;
  #pragma unroll
  for (int i = 0; i < 16; ++i)
    Tt[tn][tk*16 + i] = src[(size_t)(k0 + tk*16 + i) * N + ncol0 + tn];
  __syncthreads();

  const int n = tid >> 2, kc = (tid & 3) * 16;
  f16x8 a0, a1;
  #pragma unroll
  for (int i = 0; i < 8; ++i) {
    a0[i] = (f16_t)Tt[n][kc + i];
    a1[i] = (f16_t)Tt[n][kc + 8 + i];
  }
  const size_t ob = (size_t)(orow0 + n) * 1024 + k0 + kc;
  *(f16x8*)&wtT[ob]     = a0;
  *(f16x8*)&wtT[ob + 8] = a1;
}

// ---------------------------------------------------------------------------
// Kernel 1: QKV projection fp16 GEMM, WIDE SLOTS (128 cols = 2 heads/block).
// grid 512 XCD-swizzled = 32 row-tiles x 16 wide-slots (ws<8 Q, <12 K, else V).
// Per-head RMSNorm + RoPE epilogue; V stored kv-permuted for lane-local PV.
// ---------------------------------------------------------------------------
__global__ __launch_bounds__(256)
void qkv_kernel(const f16_t* __restrict__ hsf, const f16_t* __restrict__ wtT,
                const float* __restrict__ cosp, const float* __restrict__ sinp,
                const float* __restrict__ qnw, const float* __restrict__ knw,
                f16_t* __restrict__ q_o, f16_t* __restrict__ k_o,
                f16_t* __restrict__ vt_o)
{
  __shared__ __align__(16) f16_t Ah[128][64];  // 16 KB
  __shared__ __align__(16) f16_t Bh[128][64];  // 16 KB

  const int tid = threadIdx.x;
  const int lane = tid & 63, wave = tid >> 6;
  const int lo16 = lane & 15, hi4 = lane >> 4;
  const int lin = blockIdx.x;
  const int swz = (lin & 7) * 64 + (lin >> 3);   // 512 = 8 * 64, bijective
  const int m0 = (swz >> 4) * 128;
  const int ws = swz & 15;
  const int orow = ws * 128;

  int kind, hd0;
  if (ws < 8)       { kind = 0; hd0 = ws*2; }
  else if (ws < 12) { kind = 1; hd0 = (ws-8)*2; }
  else              { kind = 2; hd0 = (ws-12)*2; }

  f32x4 acc[2][8];
  #pragma unroll
  for (int qb = 0; qb < 2; ++qb)
    #pragma unroll
    for (int j = 0; j < 8; ++j) acc[qb][j] = f32x4{0.f, 0.f, 0.f, 0.f};

  const int ri = lane >> 3, pc = lane & 7;
  const int lcs = (pc ^ ri) * 8;   // pre-swizzled global chunk
  size_t aoff4[4]; f16_t* aldst4[4];
  size_t boff4[4]; f16_t* bldst4[4];
  #pragma unroll
  for (int q = 0; q < 4; ++q) {
    aoff4[q] = (size_t)(m0 + wave*32 + q*8 + ri) * PHID + lcs;
    aldst4[q] = &Ah[wave*32 + q*8][0];
    boff4[q] = (size_t)(orow + wave*32 + q*8 + ri) * 1024 + lcs;
    bldst4[q] = &Bh[wave*32 + q*8][0];
  }

  const int rsw = lo16 & 7;

  for (int k0 = 0; k0 < PHID; k0 += 64) {
    __syncthreads();
    #pragma unroll
    for (int q = 0; q < 4; ++q) gl16(hsf + aoff4[q] + k0, aldst4[q]);
    #pragma unroll
    for (int q = 0; q < 4; ++q) gl16(wtT + boff4[q] + k0, bldst4[q]);
    __syncthreads();

    #pragma unroll
    for (int t = 0; t < 2; ++t) {
      const int ccol = ((t*4 + hi4) ^ rsw) * 8;
      f16x8 ah[2];
      #pragma unroll
      for (int qb = 0; qb < 2; ++qb)
        ah[qb] = *(const f16x8*)&Ah[wave*32 + qb*16 + lo16][ccol];
      #pragma unroll
      for (int j = 0; j < 8; ++j) {
        f16x8 bh = *(const f16x8*)&Bh[j*16 + lo16][ccol];
        #pragma unroll
        for (int qb = 0; qb < 2; ++qb)
          acc[qb][j] = MFMAH(ah[qb], bh, acc[qb][j]);
      }
    }
  }

  // ---- epilogue: per-head RMSNorm + RoPE; fp16 stores ----
  float nwv[4];
  #pragma unroll
  for (int jj = 0; jj < 4; ++jj)
    nwv[jj] = (kind == 0) ? qnw[lo16 + 16*jj]
            : (kind == 1) ? knw[lo16 + 16*jj] : 1.0f;

  #pragma unroll
  for (int qb = 0; qb < 2; ++qb) {
    float sc[2][4];
    #pragma unroll
    for (int r = 0; r < 4; ++r) {
      float s0 = 0.f, s1 = 0.f;
      #pragma unroll
      for (int j = 0; j < 4; ++j) {
        s0 += acc[qb][j][r]   * acc[qb][j][r];
        s1 += acc[qb][j+4][r] * acc[qb][j+4][r];
      }
      #pragma unroll
      for (int m = 1; m < 16; m <<= 1) {
        s0 += __shfl_xor(s0, m);
        s1 += __shfl_xor(s1, m);
      }
      sc[0][r] = 1.0f / sqrtf(s0 * (1.0f/64.0f) + 1e-6f);
      sc[1][r] = 1.0f / sqrtf(s1 * (1.0f/64.0f) + 1e-6f);
    }

    float y[8][4];
    #pragma unroll
    for (int j = 0; j < 8; ++j)
      #pragma unroll
      for (int r = 0; r < 4; ++r)
        y[j][r] = acc[qb][j][r] * sc[j>>2][r] * nwv[j&3];

    if (kind == 2) {
      #pragma unroll
      for (int r = 0; r < 4; ++r) {
        int mg = m0 + wave*32 + qb*16 + hi4*4 + r;
        int b = mg >> 11, sq = mg & 2047;
        int g = sq & 63;
        int sp = (g & 3) | (((g >> 4) & 1) << 2) | (((g >> 2) & 1) << 3)
               | (((g >> 3) & 1) << 4) | (g & 32);
        int sq2 = (sq & ~63) | sp;
        #pragma unroll
        for (int j = 0; j < 8; ++j) {
          int d = lo16 + 16*(j & 3), hd = hd0 + (j >> 2);
          vt_o[((size_t)((b*PKV + hd)*PD + d))*PS + sq2] = (f16_t)y[j][r];
        }
      }
    } else {
      #pragma unroll
      for (int r = 0; r < 4; ++r) {
        int mg = m0 + wave*32 + qb*16 + hi4*4 + r;
        int b = mg >> 11, sq = mg & 2047;
        const float* cp = &cosp[(size_t)mg * PD];
        const float* sp = &sinp[(size_t)mg * PD];
        float z[8];
        #pragma unroll
        for (int j = 0; j < 8; ++j) {
          int d = lo16 + 16*(j & 3);
          float c = cp[d], s = sp[d];
          float rot = (j & 1) ? y[j-1][r] : -y[j+1][r];
          z[j] = y[j][r] * c + rot * s;
        }
        #pragma unroll
        for (int j = 0; j < 8; ++j) {
          int d = lo16 + 16*(j & 3), hd = hd0 + (j >> 2);
          if (kind == 0) {
            size_t idx = ((size_t)(b*PH + hd)*PS + sq)*PD + d;
            q_o[idx] = (f16_t)(z[j] * LOG2E);   // exp2-domain fold
          } else {
            size_t idx = ((size_t)(b*PKV + hd)*PS + sq)*PD + d;
            k_o[idx] = (f16_t)z[j];
          }
        }
      }
    }
  }
}

// ---------------------------------------------------------------------------
// Kernel 2: flash attention. gl16 double-buffered K/V (XOR-swizzled),
// lane-local P. VALU-lean softmax (r11 body) at 4 blocks/CU: grid 1024 fits
// the 256-CU machine exactly at launch_bounds(256,4) -> zero residency tail.
// LDS 32 KB.
// ---------------------------------------------------------------------------
__global__ __launch_bounds__(256, 4)
void attn_kernel(const f16_t* __restrict__ q_g, const f16_t* __restrict__ k_g,
                 const f16_t* __restrict__ vt_g,
                 f16_t* __restrict__ op, float2* __restrict__ ml)
{
  __shared__ __align__(16) char lds_raw[32768];
  f16_t (*Ks)[64][64] = (f16_t (*)[64][64])lds_raw;             // [2][64][64]
  f16_t (*Vs)[64][64] = (f16_t (*)[64][64])(lds_raw + 16384);   // [2][64][64]
  f16_t (*Ob)[72]     = (f16_t (*)[72])lds_raw;                 // epilogue overlay

  const int tid = threadIdx.x, lane = tid & 63, wave = tid >> 6;
  const int lo16 = lane & 15, hi4 = lane >> 4;
  const int lin = blockIdx.x;
  const int swz = (lin & 7) * 128 + (lin >> 3);
  const int qt = swz & 15;
  const int bh = (swz >> 4) & 31;
  const int ks = swz >> 9;
  const int b = bh >> 4, h = bh & 15, kvh = h >> 1;   // GQA groups=2

  f16x8 qf[2][2];
  #pragma unroll
  for (int qb = 0; qb < 2; ++qb) {
    const size_t qbase = ((size_t)(b*PH + h)*PS + qt*128 + wave*32 + qb*16 + lo16) * PD;
    #pragma unroll
    for (int t = 0; t < 2; ++t)
      qf[qb][t] = *(const f16x8*)&q_g[qbase + t*32 + hi4*8];
  }

  f32x4 o[2][4], lsum[2];
  float mq[2] = {0.f, 0.f};   // log2-domain running max
  #pragma unroll
  for (int qb = 0; qb < 2; ++qb) {
    lsum[qb] = f32x4{0.f, 0.f, 0.f, 0.f};
    #pragma unroll
    for (int j = 0; j < 4; ++j) o[qb][j] = f32x4{0.f, 0.f, 0.f, 0.f};
  }

  f16x8 ONES;
  #pragma unroll
  for (int e = 0; e < 8; ++e) ONES[e] = (f16_t)1.0f;

  const int ri = lane >> 3;
  const int lcs = ((lane & 7) ^ ri) * 8;   // pre-swizzled global chunk
  const size_t kbase = (size_t)(b*PKV + kvh) * PS * PD + (size_t)ks * 1024 * PD;
  const size_t vbase = (size_t)(b*PKV + kvh) * PD * PS + (size_t)ks * 1024;

  auto STAGE = [&](int kt, int buf) {
    const f16_t* kp = k_g + kbase + (size_t)kt * 64 * PD;
    const f16_t* vp = vt_g + vbase + kt * 64;
    #pragma unroll
    for (int i = 0; i < 2; ++i) {
      const int st = wave*2 + i;   // stripe of 8 rows
      gl16(kp + (st*8 + ri)*PD + lcs, &Ks[buf][st*8][0]);
      gl16(vp + (size_t)(st*8 + ri)*PS + lcs, &Vs[buf][st*8][0]);
    }
  };

  STAGE(0, 0);
  int cur = 0;
  const int rsw = lo16 & 7;

  for (int kt = 0; kt < 16; ++kt) {
    __syncthreads();   // buf[cur] ready; prev reads of buf[cur^1] done
    if (kt + 1 < 16) STAGE(kt + 1, cur ^ 1);

    // QK^T swapped with -mq folded into the C operand: sacc = K.Q - mq
    f32x4 sacc[2][4];
    __builtin_amdgcn_s_setprio(1);
    #pragma unroll
    for (int j = 0; j < 4; ++j) {
      f16x8 kf0 = *(const f16x8*)&Ks[cur][j*16 + lo16][(hi4 ^ rsw) * 8];
      f16x8 kf1 = *(const f16x8*)&Ks[cur][j*16 + lo16][((4 + hi4) ^ rsw) * 8];
      #pragma unroll
      for (int qb = 0; qb < 2; ++qb) {
        f32x4 mc = {-mq[qb], -mq[qb], -mq[qb], -mq[qb]};
        sacc[qb][j] = MFMAH(kf1, qf[qb][1], MFMAH(kf0, qf[qb][0], mc));
      }
    }
    __builtin_amdgcn_s_setprio(0);

    // softmax: scores arrive pre-shifted; exp+pack straight to fp16 pairs.
    f16x8 pa[2][2];
    #pragma unroll
    for (int qb = 0; qb < 2; ++qb) {
      // max3-shaped reduction over the 16 shifted scores
      float m0_ = fmaxf(fmaxf(sacc[qb][0][0], sacc[qb][0][1]), sacc[qb][0][2]);
      float m1_ = fmaxf(fmaxf(sacc[qb][0][3], sacc[qb][1][0]), sacc[qb][1][1]);
      float m2_ = fmaxf(fmaxf(sacc[qb][1][2], sacc[qb][1][3]), sacc[qb][2][0]);
      float m3_ = fmaxf(fmaxf(sacc[qb][2][1], sacc[qb][2][2]), sacc[qb][2][3]);
      float m4_ = fmaxf(fmaxf(sacc[qb][3][0], sacc[qb][3][1]), sacc[qb][3][2]);
      float tm  = fmaxf(fmaxf(m0_, m1_), m2_);
      tm = fmaxf(fmaxf(tm, m3_), m4_);
      tm = fmaxf(tm, sacc[qb][3][3]);
      tm = fmaxf(tm, __shfl_xor(tm, 16));
      tm = fmaxf(tm, __shfl_xor(tm, 32));

      if (!__all(tm <= 8.0f)) {
        // rescale path (rare after first tile)
        float tmx = fmaxf(tm, 0.f);
        float alpha = __builtin_amdgcn_exp2f(-tmx);
        lsum[qb] *= alpha;
        #pragma unroll
        for (int jd = 0; jd < 4; ++jd) o[qb][jd] *= alpha;
        mq[qb] += tmx;
        #pragma unroll
        for (int t = 0; t < 2; ++t) {
          union { fp16v2 h[4]; f16x8 v; } u;
          #pragma unroll
          for (int pr = 0; pr < 2; ++pr) {
            float p0 = __builtin_amdgcn_exp2f(sacc[qb][2*t+pr][0] - tmx);
            float p1 = __builtin_amdgcn_exp2f(sacc[qb][2*t+pr][1] - tmx);
            float p2 = __builtin_amdgcn_exp2f(sacc[qb][2*t+pr][2] - tmx);
            float p3 = __builtin_amdgcn_exp2f(sacc[qb][2*t+pr][3] - tmx);
            u.h[pr*2]   = __builtin_amdgcn_cvt_pkrtz(p0, p1);
            u.h[pr*2+1] = __builtin_amdgcn_cvt_pkrtz(p2, p3);
          }
          pa[qb][t] = u.v;
        }
      } else {
        // common path: no subtraction at all
        #pragma unroll
        for (int t = 0; t < 2; ++t) {
          union { fp16v2 h[4]; f16x8 v; } u;
          #pragma unroll
          for (int pr = 0; pr < 2; ++pr) {
            float p0 = __builtin_amdgcn_exp2f(sacc[qb][2*t+pr][0]);
            float p1 = __builtin_amdgcn_exp2f(sacc[qb][2*t+pr][1]);
            float p2 = __builtin_amdgcn_exp2f(sacc[qb][2*t+pr][2]);
            float p3 = __builtin_amdgcn_exp2f(sacc[qb][2*t+pr][3]);
            u.h[pr*2]   = __builtin_amdgcn_cvt_pkrtz(p0, p1);
            u.h[pr*2+1] = __builtin_amdgcn_cvt_pkrtz(p2, p3);
          }
          pa[qb][t] = u.v;
        }
      }
    }

    // PV + l-accumulation (ones-row MFMA sums P over kv; no VALU adds)
    __builtin_amdgcn_s_setprio(1);
    #pragma unroll
    for (int jd = 0; jd < 4; ++jd) {
      #pragma unroll
      for (int t = 0; t < 2; ++t) {
        f16x8 vf = *(const f16x8*)&Vs[cur][jd*16 + lo16][((t*4 + hi4) ^ rsw) * 8];
        #pragma unroll
        for (int qb = 0; qb < 2; ++qb)
          o[qb][jd] = MFMAH(vf, pa[qb][t], o[qb][jd]);
      }
    }
    #pragma unroll
    for (int qb = 0; qb < 2; ++qb)
      #pragma unroll
      for (int t = 0; t < 2; ++t)
        lsum[qb] = MFMAH(ONES, pa[qb][t], lsum[qb]);
    __builtin_amdgcn_s_setprio(0);

    cur ^= 1;
  }

  // ---- epilogue: (m,l) + normalized O via LDS transpose bounce ----
  __syncthreads();   // all waves done with K/V tiles; overlay is safe
  const int rbase = bh*PS + qt*128 + wave*32;
  if (hi4 == 0) {
    #pragma unroll
    for (int qb = 0; qb < 2; ++qb)
      ml[(size_t)ks*PR + rbase + qb*16 + lo16] = float2{mq[qb], lsum[qb][0]};
  }
  #pragma unroll
  for (int qb = 0; qb < 2; ++qb) {
    float inv = 1.0f / lsum[qb][0];
    #pragma unroll
    for (int jd = 0; jd < 4; ++jd)
      #pragma unroll
      for (int rp = 0; rp < 2; ++rp)
        *(f16x2*)&Ob[wave*32 + qb*16 + lo16][jd*16 + hi4*4 + 2*rp] =
            f16x2{(f16_t)(o[qb][jd][2*rp] * inv), (f16_t)(o[qb][jd][2*rp+1] * inv)};
  }
  {
    const int row = lane >> 1, half = lane & 1;
    const size_t gb_ = ((size_t)ks*PR + rbase + row) * PD + half*32;
    #pragma unroll
    for (int c = 0; c < 4; ++c)
      *(f16x8*)&op[gb_ + c*8] = *(const f16x8*)&Ob[wave*32 + row][half*32 + c*8];
  }
}

// ---------------------------------------------------------------------------
// Kernel 3: merge kv-split partials (normalized O + m,l in log2 domain).
// ---------------------------------------------------------------------------
__global__ __launch_bounds__(256)
void merge_kernel(const f16_t* __restrict__ op, const float2* __restrict__ ml,
                  f16_t* __restrict__ ao)
{
  const int gid = blockIdx.x * 256 + threadIdx.x;
  const int row = gid >> 3, oct = gid & 7;
  float2 e0 = ml[row], e1 = ml[PR + row];
  float M = fmaxf(e0.x, e1.x);
  float c0 = __builtin_amdgcn_exp2f(e0.x - M) * e0.y;
  float c1 = __builtin_amdgcn_exp2f(e1.x - M) * e1.y;
  float inv = 1.0f / (c0 + c1);
  c0 *= inv; c1 *= inv;
  f16x8 a = *(const f16x8*)&op[(size_t)row*PD + oct*8];
  f16x8 bq = *(const f16x8*)&op[(size_t)(PR + row)*PD + oct*8];
  f16x8 r;
  #pragma unroll
  for (int i = 0; i < 8; ++i)
    r[i] = (f16_t)(c0 * (float)a[i] + c1 * (float)bq[i]);
  const int bh = row >> 11, sq = row & 2047;
  const int b = bh >> 4, h = bh & 15;
  *(f16x8*)&ao[((size_t)(b*PS + sq))*PHID + h*PD + oct*8] = r;
}

// ---------------------------------------------------------------------------
// Kernel 4: out-projection, fp16 GEMM (ao x WoT) -> fp32. qkv-style staging:
// BK=64, gl16 with XOR swizzle. grid 512 XCD-swizzled. LDS 24 KB.
// ---------------------------------------------------------------------------
__global__ __launch_bounds__(256)
void oproj_kernel(const f16_t* __restrict__ ao, const f16_t* __restrict__ woT,
                  float* __restrict__ out)
{
  __shared__ __align__(16) f16_t As[128][64];  // 16 KB
  __shared__ __align__(16) f16_t Bs[64][64];   // 8 KB

  const int tid = threadIdx.x;
  const int lane = tid & 63, wave = tid >> 6;
  const int lo16 = lane & 15, hi4 = lane >> 4;
  const int lin = blockIdx.x;
  const int swz = (lin & 7) * 64 + (lin >> 3);
  const int m0 = (swz >> 4) * 128;
  const int col0 = (swz & 15) * 64;

  f32x4 acc[2][4];
  #pragma unroll
  for (int qb = 0; qb < 2; ++qb)
    #pragma unroll
    for (int j = 0; j < 4; ++j) acc[qb][j] = f32x4{0.f, 0.f, 0.f, 0.f};

  const int ri = lane >> 3, pc = lane & 7;
  const int lcs = (pc ^ ri) * 8;   // pre-swizzled global chunk
  size_t aoff4[4]; f16_t* aldst4[4];
  #pragma unroll
  for (int q = 0; q < 4; ++q) {
    aoff4[q] = (size_t)(m0 + wave*32 + q*8 + ri) * PHID + lcs;
    aldst4[q] = &As[wave*32 + q*8][0];
  }
  size_t boff[2]; int brow[2];
  #pragma unroll
  for (int q = 0; q < 2; ++q) {
    brow[q] = wave*16 + q*8;
    boff[q] = (size_t)(col0 + brow[q] + ri) * 1024 + lcs;
  }

  const int rsw = lo16 & 7;

  for (int k0 = 0; k0 < PHID; k0 += 64) {
    __syncthreads();
    #pragma unroll
    for (int q = 0; q < 4; ++q) gl16(ao + aoff4[q] + k0, aldst4[q]);
    #pragma unroll
    for (int q = 0; q < 2; ++q) gl16(woT + boff[q] + k0, &Bs[brow[q]][0]);
    __syncthreads();

    #pragma unroll
    for (int t = 0; t < 2; ++t) {
      const int ccol = ((t*4 + hi4) ^ rsw) * 8;
      f16x8 a[2];
      #pragma unroll
      for (int qb = 0; qb < 2; ++qb)
        a[qb] = *(const f16x8*)&As[wave*32 + qb*16 + lo16][ccol];
      #pragma unroll
      for (int j = 0; j < 4; ++j) {
        f16x8 bb = *(const f16x8*)&Bs[j*16 + lo16][ccol];
        #pragma unroll
        for (int qb = 0; qb < 2; ++qb)
          acc[qb][j] = MFMAH(a[qb], bb, acc[qb][j]);
      }
    }
  }

  #pragma unroll
  for (int qb = 0; qb < 2; ++qb)
    #pragma unroll
    for (int r = 0; r < 4; ++r) {
      int mg = m0 + wave*32 + qb*16 + hi4*4 + r;
      #pragma unroll
      for (int j = 0; j < 4; ++j)
        out[(size_t)mg*PHID + col0 + lo16 + 16*j] = acc[qb][j][r];
    }
}

// ---------------------------------------------------------------------------
extern "C" void kernel_launch(void* const* d_in, const int* in_sizes, int n_in,
                              void* d_out, int out_size, void* d_ws, size_t ws_size,
                              hipStream_t stream) {
  (void)in_sizes; (void)n_in; (void)out_size; (void)ws_size;
  const float* hs   = (const float*)d_in[0];
  const float* cosp = (const float*)d_in[1];
  const float* sinp = (const float*)d_in[2];
  // d_in[3] position_ids: only shape[-1]=2 used (NDIM=2 hardcoded)
  const float* Wq   = (const float*)d_in[4];
  const float* Wk   = (const float*)d_in[5];
  const float* Wv   = (const float*)d_in[6];
  const float* Wo   = (const float*)d_in[7];
  const float* qnw  = (const float*)d_in[8];
  const float* knw  = (const float*)d_in[9];
  float* out = (float*)d_out;

  const size_t QN = (size_t)PB*PH*PS*PD;    // 4,194,304 (== PR*PD == PM*PHID)
  const size_t KN = (size_t)PB*PKV*PS*PD;   // 2,097,152
  const size_t HN = (size_t)PM*PHID;        // 4,194,304
  char* wsb = (char*)d_ws;
  f16_t*  qv  = (f16_t*)wsb;                   // QN fp16 (8 MB)
  f16_t*  kv  = qv + QN;                       // KN (4 MB)
  f16_t*  vt  = kv + KN;                       // KN (4 MB)
  f16_t*  hsf = vt + KN;                       // HN (8 MB, dead after qkv)
  f16_t*  wtT = hsf + HN;                      // 3072*1024 (6 MB; rows 2048+ live)
  f16_t*  op  = wtT + (size_t)3072*1024;       // 2*QN (16 MB)
  float2* ml  = (float2*)(op + 2*QN);          // 2*PR float2 (1 MB)
  f16_t*  ao  = qv;   // alias: attn done with Q before merge (stream-ordered)
  const f16_t* woT = wtT + (size_t)2048*1024;

  convert_hs<<<dim3(2048), 256, 0, stream>>>(hs, hsf);
  convert_w <<<dim3(768),  256, 0, stream>>>(Wq, Wk, Wv, Wo, wtT);
  qkv_kernel<<<dim3(512),  256, 0, stream>>>(hsf, wtT, cosp, sinp,
                                             qnw, knw, qv, kv, vt);
  attn_kernel<<<dim3(1024), 256, 0, stream>>>(qv, kv, vt, op, ml);
  merge_kernel<<<dim3(PR*8/256), 256, 0, stream>>>(op, ml, ao);
  oproj_kernel<<<dim3(512), 256, 0, stream>>>(ao, woT, out);
}

// Round 13
// 117.549 us; speedup vs baseline: 1.1761x; 1.1761x over previous
//
#include <hip/hip_runtime.h>

// Problem constants
#define PB 2
#define PS 2048
#define PHID 1024
#define PH 16
#define PKV 8
#define PD 64
#define PM (PB*PS)    // 4096
#define PR (PB*PH*PS) // 65536 q-rows total

typedef _Float16 f16_t;
typedef _Float16 f16x8 __attribute__((ext_vector_type(8)));
typedef _Float16 f16x2 __attribute__((ext_vector_type(2)));
typedef float f32x4 __attribute__((ext_vector_type(4)));

#define MFMAH(a,b,c)  __builtin_amdgcn_mfma_f32_16x16x32_f16((a),(b),(c),0,0,0)
#define LOG2E 1.44269504f

// global -> LDS direct copy, 16B per lane (dst = uniform base + lane*16).
__device__ __forceinline__ void gl16(const f16_t* g, f16_t* l) {
  __builtin_amdgcn_global_load_lds(
      (const __attribute__((address_space(1))) void*)g,
      (__attribute__((address_space(3))) void*)l, 16, 0, 0);
}

// ---------------------------------------------------------------------------
// Kernel 0a: hs fp32 -> fp16.
// ---------------------------------------------------------------------------
__global__ __launch_bounds__(256)
void convert_hs(const float* __restrict__ hs, f16_t* __restrict__ hf)
{
  const size_t i = ((size_t)blockIdx.x * 256 + threadIdx.x) * 8;
  float4 a = *(const float4*)&hs[i];
  float4 b = *(const float4*)&hs[i + 4];
  float xs[8] = {a.x, a.y, a.z, a.w, b.x, b.y, b.z, b.w};
  f16x8 v;
  #pragma unroll
  for (int j = 0; j < 8; ++j) v[j] = (f16_t)xs[j];
  *(f16x8*)&hf[i] = v;
}

// ---------------------------------------------------------------------------
// Kernel 0b: weights -> transposed [n][k] fp16 (rows: Wq^T 0-1023, Wk^T
// 1024-1535, Wv^T 1536-2047, Wo^T 2048-3071). grid 768.
// ---------------------------------------------------------------------------
__global__ __launch_bounds__(256)
void convert_w(const float* __restrict__ Wq, const float* __restrict__ Wk,
               const float* __restrict__ Wv, const float* __restrict__ Wo,
               f16_t* __restrict__ wtT)
{
  __shared__ float Tt[64][68];
  const int tid = threadIdx.x;
  const int slot = blockIdx.x >> 4, k0 = (blockIdx.x & 15) * 64;

  const float* src; int N, ncol0, orow0;
  if (slot < 16)      { src = Wq; N = 1024; ncol0 = slot*64;      orow0 = slot*64; }
  else if (slot < 24) { src = Wk; N = 512;  ncol0 = (slot-16)*64; orow0 = 1024 + (slot-16)*64; }
  else if (slot < 32) { src = Wv; N = 512;  ncol0 = (slot-24)*64; orow0 = 1536 + (slot-24)*64; }
  else                { src = Wo; N = 1024; ncol0 = (slot-32)*64; orow0 = 2048 + (slot-32)*64; }

  const int tk = tid >> 6, tn = tid & 63;
  #pragma unroll
  for (int i = 0; i < 16; ++i)
    Tt[tn][tk*16 + i] = src[(size_t)(k0 + tk*16 + i) * N + ncol0 + tn];
  __syncthreads();

  const int n = tid >> 2, kc = (tid & 3) * 16;
  f16x8 a0, a1;
  #pragma unroll
  for (int i = 0; i < 8; ++i) {
    a0[i] = (f16_t)Tt[n][kc + i];
    a1[i] = (f16_t)Tt[n][kc + 8 + i];
  }
  const size_t ob = (size_t)(orow0 + n) * 1024 + k0 + kc;
  *(f16x8*)&wtT[ob]     = a0;
  *(f16x8*)&wtT[ob + 8] = a1;
}

// ---------------------------------------------------------------------------
// Kernel 1: QKV projection fp16 GEMM, WIDE SLOTS (128 cols = 2 heads/block).
// grid 512 XCD-swizzled = 32 row-tiles x 16 wide-slots (ws<8 Q, <12 K, else V).
// Per-head RMSNorm + RoPE epilogue; V stored kv-permuted for lane-local PV.
// ---------------------------------------------------------------------------
__global__ __launch_bounds__(256)
void qkv_kernel(const f16_t* __restrict__ hsf, const f16_t* __restrict__ wtT,
                const float* __restrict__ cosp, const float* __restrict__ sinp,
                const float* __restrict__ qnw, const float* __restrict__ knw,
                f16_t* __restrict__ q_o, f16_t* __restrict__ k_o,
                f16_t* __restrict__ vt_o)
{
  __shared__ __align__(16) f16_t Ah[128][64];  // 16 KB
  __shared__ __align__(16) f16_t Bh[128][64];  // 16 KB

  const int tid = threadIdx.x;
  const int lane = tid & 63, wave = tid >> 6;
  const int lo16 = lane & 15, hi4 = lane >> 4;
  const int lin = blockIdx.x;
  const int swz = (lin & 7) * 64 + (lin >> 3);   // 512 = 8 * 64, bijective
  const int m0 = (swz >> 4) * 128;
  const int ws = swz & 15;
  const int orow = ws * 128;

  int kind, hd0;
  if (ws < 8)       { kind = 0; hd0 = ws*2; }
  else if (ws < 12) { kind = 1; hd0 = (ws-8)*2; }
  else              { kind = 2; hd0 = (ws-12)*2; }

  f32x4 acc[2][8];
  #pragma unroll
  for (int qb = 0; qb < 2; ++qb)
    #pragma unroll
    for (int j = 0; j < 8; ++j) acc[qb][j] = f32x4{0.f, 0.f, 0.f, 0.f};

  const int ri = lane >> 3, pc = lane & 7;
  const int lcs = (pc ^ ri) * 8;   // pre-swizzled global chunk
  size_t aoff4[4]; f16_t* aldst4[4];
  size_t boff4[4]; f16_t* bldst4[4];
  #pragma unroll
  for (int q = 0; q < 4; ++q) {
    aoff4[q] = (size_t)(m0 + wave*32 + q*8 + ri) * PHID + lcs;
    aldst4[q] = &Ah[wave*32 + q*8][0];
    boff4[q] = (size_t)(orow + wave*32 + q*8 + ri) * 1024 + lcs;
    bldst4[q] = &Bh[wave*32 + q*8][0];
  }

  const int rsw = lo16 & 7;

  for (int k0 = 0; k0 < PHID; k0 += 64) {
    __syncthreads();
    #pragma unroll
    for (int q = 0; q < 4; ++q) gl16(hsf + aoff4[q] + k0, aldst4[q]);
    #pragma unroll
    for (int q = 0; q < 4; ++q) gl16(wtT + boff4[q] + k0, bldst4[q]);
    __syncthreads();

    #pragma unroll
    for (int t = 0; t < 2; ++t) {
      const int ccol = ((t*4 + hi4) ^ rsw) * 8;
      f16x8 ah[2];
      #pragma unroll
      for (int qb = 0; qb < 2; ++qb)
        ah[qb] = *(const f16x8*)&Ah[wave*32 + qb*16 + lo16][ccol];
      #pragma unroll
      for (int j = 0; j < 8; ++j) {
        f16x8 bh = *(const f16x8*)&Bh[j*16 + lo16][ccol];
        #pragma unroll
        for (int qb = 0; qb < 2; ++qb)
          acc[qb][j] = MFMAH(ah[qb], bh, acc[qb][j]);
      }
    }
  }

  // ---- epilogue: per-head RMSNorm + RoPE; fp16 stores ----
  float nwv[4];
  #pragma unroll
  for (int jj = 0; jj < 4; ++jj)
    nwv[jj] = (kind == 0) ? qnw[lo16 + 16*jj]
            : (kind == 1) ? knw[lo16 + 16*jj] : 1.0f;

  #pragma unroll
  for (int qb = 0; qb < 2; ++qb) {
    float sc[2][4];
    #pragma unroll
    for (int r = 0; r < 4; ++r) {
      float s0 = 0.f, s1 = 0.f;
      #pragma unroll
      for (int j = 0; j < 4; ++j) {
        s0 += acc[qb][j][r]   * acc[qb][j][r];
        s1 += acc[qb][j+4][r] * acc[qb][j+4][r];
      }
      #pragma unroll
      for (int m = 1; m < 16; m <<= 1) {
        s0 += __shfl_xor(s0, m);
        s1 += __shfl_xor(s1, m);
      }
      sc[0][r] = 1.0f / sqrtf(s0 * (1.0f/64.0f) + 1e-6f);
      sc[1][r] = 1.0f / sqrtf(s1 * (1.0f/64.0f) + 1e-6f);
    }

    float y[8][4];
    #pragma unroll
    for (int j = 0; j < 8; ++j)
      #pragma unroll
      for (int r = 0; r < 4; ++r)
        y[j][r] = acc[qb][j][r] * sc[j>>2][r] * nwv[j&3];

    if (kind == 2) {
      #pragma unroll
      for (int r = 0; r < 4; ++r) {
        int mg = m0 + wave*32 + qb*16 + hi4*4 + r;
        int b = mg >> 11, sq = mg & 2047;
        int g = sq & 63;
        int sp = (g & 3) | (((g >> 4) & 1) << 2) | (((g >> 2) & 1) << 3)
               | (((g >> 3) & 1) << 4) | (g & 32);
        int sq2 = (sq & ~63) | sp;
        #pragma unroll
        for (int j = 0; j < 8; ++j) {
          int d = lo16 + 16*(j & 3), hd = hd0 + (j >> 2);
          vt_o[((size_t)((b*PKV + hd)*PD + d))*PS + sq2] = (f16_t)y[j][r];
        }
      }
    } else {
      #pragma unroll
      for (int r = 0; r < 4; ++r) {
        int mg = m0 + wave*32 + qb*16 + hi4*4 + r;
        int b = mg >> 11, sq = mg & 2047;
        const float* cp = &cosp[(size_t)mg * PD];
        const float* sp = &sinp[(size_t)mg * PD];
        float z[8];
        #pragma unroll
        for (int j = 0; j < 8; ++j) {
          int d = lo16 + 16*(j & 3);
          float c = cp[d], s = sp[d];
          float rot = (j & 1) ? y[j-1][r] : -y[j+1][r];
          z[j] = y[j][r] * c + rot * s;
        }
        #pragma unroll
        for (int j = 0; j < 8; ++j) {
          int d = lo16 + 16*(j & 3), hd = hd0 + (j >> 2);
          if (kind == 0) {
            size_t idx = ((size_t)(b*PH + hd)*PS + sq)*PD + d;
            q_o[idx] = (f16_t)(z[j] * LOG2E);   // exp2-domain fold
          } else {
            size_t idx = ((size_t)(b*PKV + hd)*PS + sq)*PD + d;
            k_o[idx] = (f16_t)z[j];
          }
        }
      }
    }
  }
}

// ---------------------------------------------------------------------------
// Kernel 2: flash attention — EXACT round-8 body (55.1 us measured, VGPR 60,
// zero spills at 4 blocks/CU). gl16 double-buffered K/V (XOR-swizzled),
// lane-local P via pre-permuted V, exp2 softmax + defer-max, zero-C first
// MFMA, fused exp+pack. grid 1024 XCD-swizzled. LDS 32 KB.
// ---------------------------------------------------------------------------
__global__ __launch_bounds__(256, 4)
void attn_kernel(const f16_t* __restrict__ q_g, const f16_t* __restrict__ k_g,
                 const f16_t* __restrict__ vt_g,
                 f16_t* __restrict__ op, float2* __restrict__ ml)
{
  __shared__ __align__(16) char lds_raw[32768];
  f16_t (*Ks)[64][64] = (f16_t (*)[64][64])lds_raw;             // [2][64][64]
  f16_t (*Vs)[64][64] = (f16_t (*)[64][64])(lds_raw + 16384);   // [2][64][64]
  f16_t (*Ob)[72]     = (f16_t (*)[72])lds_raw;                 // epilogue overlay

  const int tid = threadIdx.x, lane = tid & 63, wave = tid >> 6;
  const int lo16 = lane & 15, hi4 = lane >> 4;
  const int lin = blockIdx.x;
  const int swz = (lin & 7) * 128 + (lin >> 3);
  const int qt = swz & 15;
  const int bh = (swz >> 4) & 31;
  const int ks = swz >> 9;
  const int b = bh >> 4, h = bh & 15, kvh = h >> 1;   // GQA groups=2

  f16x8 qf[2][2];
  #pragma unroll
  for (int qb = 0; qb < 2; ++qb) {
    const size_t qbase = ((size_t)(b*PH + h)*PS + qt*128 + wave*32 + qb*16 + lo16) * PD;
    #pragma unroll
    for (int t = 0; t < 2; ++t)
      qf[qb][t] = *(const f16x8*)&q_g[qbase + t*32 + hi4*8];
  }

  f32x4 o[2][4];
  float mq[2] = {-1e30f, -1e30f}, lq[2] = {0.f, 0.f};
  #pragma unroll
  for (int qb = 0; qb < 2; ++qb)
    #pragma unroll
    for (int j = 0; j < 4; ++j) o[qb][j] = f32x4{0.f, 0.f, 0.f, 0.f};

  const f32x4 FZ = {0.f, 0.f, 0.f, 0.f};   // constant C for first MFMA

  const int ri = lane >> 3;
  const int lcs = ((lane & 7) ^ ri) * 8;   // pre-swizzled global chunk
  const size_t kbase = (size_t)(b*PKV + kvh) * PS * PD + (size_t)ks * 1024 * PD;
  const size_t vbase = (size_t)(b*PKV + kvh) * PD * PS + (size_t)ks * 1024;

  auto STAGE = [&](int kt, int buf) {
    const f16_t* kp = k_g + kbase + (size_t)kt * 64 * PD;
    const f16_t* vp = vt_g + vbase + kt * 64;
    #pragma unroll
    for (int i = 0; i < 2; ++i) {
      const int st = wave*2 + i;   // stripe of 8 rows
      gl16(kp + (st*8 + ri)*PD + lcs, &Ks[buf][st*8][0]);
      gl16(vp + (size_t)(st*8 + ri)*PS + lcs, &Vs[buf][st*8][0]);
    }
  };

  STAGE(0, 0);
  int cur = 0;
  const int rsw = lo16 & 7;

  for (int kt = 0; kt < 16; ++kt) {
    __syncthreads();   // buf[cur] ready; prev reads of buf[cur^1] done
    if (kt + 1 < 16) STAGE(kt + 1, cur ^ 1);

    // QK^T swapped: sacc[qb][j][r] = S'[kv = 16j + 4hi4 + r][q = 16qb + lo16]
    // first MFMA of each chain uses constant-zero C (no per-iter acc init)
    f32x4 sacc[2][4];
    __builtin_amdgcn_s_setprio(1);
    #pragma unroll
    for (int j = 0; j < 4; ++j) {
      f16x8 kf0 = *(const f16x8*)&Ks[cur][j*16 + lo16][(hi4 ^ rsw) * 8];
      f16x8 kf1 = *(const f16x8*)&Ks[cur][j*16 + lo16][((4 + hi4) ^ rsw) * 8];
      #pragma unroll
      for (int qb = 0; qb < 2; ++qb)
        sacc[qb][j] = MFMAH(kf1, qf[qb][1], MFMAH(kf0, qf[qb][0], FZ));
    }
    __builtin_amdgcn_s_setprio(0);

    // exp2-domain online softmax with defer-max (THR=8); fused exp+pack,
    // no write-back into sacc (avoids AGPR shuttle traffic).
    f16x8 pa[2][2];
    #pragma unroll
    for (int qb = 0; qb < 2; ++qb) {
      float x0 = fmaxf(fmaxf(sacc[qb][0][0], sacc[qb][0][1]),
                       fmaxf(sacc[qb][0][2], sacc[qb][0][3]));
      float x1 = fmaxf(fmaxf(sacc[qb][1][0], sacc[qb][1][1]),
                       fmaxf(sacc[qb][1][2], sacc[qb][1][3]));
      float x2 = fmaxf(fmaxf(sacc[qb][2][0], sacc[qb][2][1]),
                       fmaxf(sacc[qb][2][2], sacc[qb][2][3]));
      float x3 = fmaxf(fmaxf(sacc[qb][3][0], sacc[qb][3][1]),
                       fmaxf(sacc[qb][3][2], sacc[qb][3][3]));
      float tm = fmaxf(fmaxf(x0, x1), fmaxf(x2, x3));
      tm = fmaxf(tm, __shfl_xor(tm, 16));
      tm = fmaxf(tm, __shfl_xor(tm, 32));
      if (!__all(tm <= mq[qb] + 8.0f)) {
        float mnew = fmaxf(mq[qb], tm);
        float alpha = __builtin_amdgcn_exp2f(mq[qb] - mnew);
        lq[qb] *= alpha;
        #pragma unroll
        for (int jd = 0; jd < 4; ++jd) o[qb][jd] *= alpha;
        mq[qb] = mnew;
      }
      float ls = 0.f;
      #pragma unroll
      for (int t = 0; t < 2; ++t) {
        f16x8 v;
        #pragma unroll
        for (int e = 0; e < 8; ++e) {
          float p = __builtin_amdgcn_exp2f(sacc[qb][2*t + (e >> 2)][e & 3] - mq[qb]);
          ls += p;
          v[e] = (f16_t)p;
        }
        pa[qb][t] = v;
      }
      ls += __shfl_xor(ls, 16);
      ls += __shfl_xor(ls, 32);
      lq[qb] += ls;
    }

    // PV: O^T = V^T(permuted) * P  (P fragments lane-local)
    __builtin_amdgcn_s_setprio(1);
    #pragma unroll
    for (int jd = 0; jd < 4; ++jd) {
      #pragma unroll
      for (int t = 0; t < 2; ++t) {
        f16x8 vf = *(const f16x8*)&Vs[cur][jd*16 + lo16][((t*4 + hi4) ^ rsw) * 8];
        #pragma unroll
        for (int qb = 0; qb < 2; ++qb)
          o[qb][jd] = MFMAH(vf, pa[qb][t], o[qb][jd]);
      }
    }
    __builtin_amdgcn_s_setprio(0);

    cur ^= 1;
  }

  // ---- epilogue: (m,l) + normalized O via LDS transpose bounce ----
  __syncthreads();   // all waves done with K/V tiles; overlay is safe
  const int rbase = bh*PS + qt*128 + wave*32;
  if (hi4 == 0) {
    #pragma unroll
    for (int qb = 0; qb < 2; ++qb)
      ml[(size_t)ks*PR + rbase + qb*16 + lo16] = float2{mq[qb], lq[qb]};
  }
  #pragma unroll
  for (int qb = 0; qb < 2; ++qb) {
    float inv = 1.0f / lq[qb];
    #pragma unroll
    for (int jd = 0; jd < 4; ++jd)
      #pragma unroll
      for (int rp = 0; rp < 2; ++rp)
        *(f16x2*)&Ob[wave*32 + qb*16 + lo16][jd*16 + hi4*4 + 2*rp] =
            f16x2{(f16_t)(o[qb][jd][2*rp] * inv), (f16_t)(o[qb][jd][2*rp+1] * inv)};
  }
  {
    const int row = lane >> 1, half = lane & 1;
    const size_t gb_ = ((size_t)ks*PR + rbase + row) * PD + half*32;
    #pragma unroll
    for (int c = 0; c < 4; ++c)
      *(f16x8*)&op[gb_ + c*8] = *(const f16x8*)&Ob[wave*32 + row][half*32 + c*8];
  }
}

// ---------------------------------------------------------------------------
// Kernel 3: merge kv-split partials (normalized O + m,l in log2 domain).
// ---------------------------------------------------------------------------
__global__ __launch_bounds__(256)
void merge_kernel(const f16_t* __restrict__ op, const float2* __restrict__ ml,
                  f16_t* __restrict__ ao)
{
  const int gid = blockIdx.x * 256 + threadIdx.x;
  const int row = gid >> 3, oct = gid & 7;
  float2 e0 = ml[row], e1 = ml[PR + row];
  float M = fmaxf(e0.x, e1.x);
  float c0 = __builtin_amdgcn_exp2f(e0.x - M) * e0.y;
  float c1 = __builtin_amdgcn_exp2f(e1.x - M) * e1.y;
  float inv = 1.0f / (c0 + c1);
  c0 *= inv; c1 *= inv;
  f16x8 a = *(const f16x8*)&op[(size_t)row*PD + oct*8];
  f16x8 bq = *(const f16x8*)&op[(size_t)(PR + row)*PD + oct*8];
  f16x8 r;
  #pragma unroll
  for (int i = 0; i < 8; ++i)
    r[i] = (f16_t)(c0 * (float)a[i] + c1 * (float)bq[i]);
  const int bh = row >> 11, sq = row & 2047;
  const int b = bh >> 4, h = bh & 15;
  *(f16x8*)&ao[((size_t)(b*PS + sq))*PHID + h*PD + oct*8] = r;
}

// ---------------------------------------------------------------------------
// Kernel 4: out-projection, fp16 GEMM (ao x WoT) -> fp32. qkv-style staging:
// BK=64, gl16 with XOR swizzle. grid 512 XCD-swizzled. LDS 24 KB.
// ---------------------------------------------------------------------------
__global__ __launch_bounds__(256)
void oproj_kernel(const f16_t* __restrict__ ao, const f16_t* __restrict__ woT,
                  float* __restrict__ out)
{
  __shared__ __align__(16) f16_t As[128][64];  // 16 KB
  __shared__ __align__(16) f16_t Bs[64][64];   // 8 KB

  const int tid = threadIdx.x;
  const int lane = tid & 63, wave = tid >> 6;
  const int lo16 = lane & 15, hi4 = lane >> 4;
  const int lin = blockIdx.x;
  const int swz = (lin & 7) * 64 + (lin >> 3);
  const int m0 = (swz >> 4) * 128;
  const int col0 = (swz & 15) * 64;

  f32x4 acc[2][4];
  #pragma unroll
  for (int qb = 0; qb < 2; ++qb)
    #pragma unroll
    for (int j = 0; j < 4; ++j) acc[qb][j] = f32x4{0.f, 0.f, 0.f, 0.f};

  const int ri = lane >> 3, pc = lane & 7;
  const int lcs = (pc ^ ri) * 8;   // pre-swizzled global chunk
  size_t aoff4[4]; f16_t* aldst4[4];
  #pragma unroll
  for (int q = 0; q < 4; ++q) {
    aoff4[q] = (size_t)(m0 + wave*32 + q*8 + ri) * PHID + lcs;
    aldst4[q] = &As[wave*32 + q*8][0];
  }
  size_t boff[2]; int brow[2];
  #pragma unroll
  for (int q = 0; q < 2; ++q) {
    brow[q] = wave*16 + q*8;
    boff[q] = (size_t)(col0 + brow[q] + ri) * 1024 + lcs;
  }

  const int rsw = lo16 & 7;

  for (int k0 = 0; k0 < PHID; k0 += 64) {
    __syncthreads();
    #pragma unroll
    for (int q = 0; q < 4; ++q) gl16(ao + aoff4[q] + k0, aldst4[q]);
    #pragma unroll
    for (int q = 0; q < 2; ++q) gl16(woT + boff[q] + k0, &Bs[brow[q]][0]);
    __syncthreads();

    #pragma unroll
    for (int t = 0; t < 2; ++t) {
      const int ccol = ((t*4 + hi4) ^ rsw) * 8;
      f16x8 a[2];
      #pragma unroll
      for (int qb = 0; qb < 2; ++qb)
        a[qb] = *(const f16x8*)&As[wave*32 + qb*16 + lo16][ccol];
      #pragma unroll
      for (int j = 0; j < 4; ++j) {
        f16x8 bb = *(const f16x8*)&Bs[j*16 + lo16][ccol];
        #pragma unroll
        for (int qb = 0; qb < 2; ++qb)
          acc[qb][j] = MFMAH(a[qb], bb, acc[qb][j]);
      }
    }
  }

  #pragma unroll
  for (int qb = 0; qb < 2; ++qb)
    #pragma unroll
    for (int r = 0; r < 4; ++r) {
      int mg = m0 + wave*32 + qb*16 + hi4*4 + r;
      #pragma unroll
      for (int j = 0; j < 4; ++j)
        out[(size_t)mg*PHID + col0 + lo16 + 16*j] = acc[qb][j][r];
    }
}

// ---------------------------------------------------------------------------
extern "C" void kernel_launch(void* const* d_in, const int* in_sizes, int n_in,
                              void* d_out, int out_size, void* d_ws, size_t ws_size,
                              hipStream_t stream) {
  (void)in_sizes; (void)n_in; (void)out_size; (void)ws_size;
  const float* hs   = (const float*)d_in[0];
  const float* cosp = (const float*)d_in[1];
  const float* sinp = (const float*)d_in[2];
  // d_in[3] position_ids: only shape[-1]=2 used (NDIM=2 hardcoded)
  const float* Wq   = (const float*)d_in[4];
  const float* Wk   = (const float*)d_in[5];
  const float* Wv   = (const float*)d_in[6];
  const float* Wo   = (const float*)d_in[7];
  const float* qnw  = (const float*)d_in[8];
  const float* knw  = (const float*)d_in[9];
  float* out = (float*)d_out;

  const size_t QN = (size_t)PB*PH*PS*PD;    // 4,194,304 (== PR*PD == PM*PHID)
  const size_t KN = (size_t)PB*PKV*PS*PD;   // 2,097,152
  const size_t HN = (size_t)PM*PHID;        // 4,194,304
  char* wsb = (char*)d_ws;
  f16_t*  qv  = (f16_t*)wsb;                   // QN fp16 (8 MB)
  f16_t*  kv  = qv + QN;                       // KN (4 MB)
  f16_t*  vt  = kv + KN;                       // KN (4 MB)
  f16_t*  hsf = vt + KN;                       // HN (8 MB, dead after qkv)
  f16_t*  wtT = hsf + HN;                      // 3072*1024 (6 MB; rows 2048+ live)
  f16_t*  op  = wtT + (size_t)3072*1024;       // 2*QN (16 MB)
  float2* ml  = (float2*)(op + 2*QN);          // 2*PR float2 (1 MB)
  f16_t*  ao  = qv;   // alias: attn done with Q before merge (stream-ordered)
  const f16_t* woT = wtT + (size_t)2048*1024;

  convert_hs<<<dim3(2048), 256, 0, stream>>>(hs, hsf);
  convert_w <<<dim3(768),  256, 0, stream>>>(Wq, Wk, Wv, Wo, wtT);
  qkv_kernel<<<dim3(512),  256, 0, stream>>>(hsf, wtT, cosp, sinp,
                                             qnw, knw, qv, kv, vt);
  attn_kernel<<<dim3(1024), 256, 0, stream>>>(qv, kv, vt, op, ml);
  merge_kernel<<<dim3(PR*8/256), 256, 0, stream>>>(op, ml, ao);
  oproj_kernel<<<dim3(512), 256, 0, stream>>>(ao, woT, out);
}

// Round 14
// 115.856 us; speedup vs baseline: 1.1932x; 1.0146x over previous
//
#include <hip/hip_runtime.h>

// Problem constants
#define PB 2
#define PS 2048
#define PHID 1024
#define PH 16
#define PKV 8
#define PD 64
#define PM (PB*PS)    // 4096
#define PR (PB*PH*PS) // 65536 q-rows total

typedef _Float16 f16_t;
typedef _Float16 f16x8 __attribute__((ext_vector_type(8)));
typedef _Float16 f16x2 __attribute__((ext_vector_type(2)));
typedef __fp16 fp16v2 __attribute__((ext_vector_type(2)));   // cvt_pkrtz native type
typedef float f32x4 __attribute__((ext_vector_type(4)));

#define MFMAH(a,b,c)  __builtin_amdgcn_mfma_f32_16x16x32_f16((a),(b),(c),0,0,0)
#define LOG2E 1.44269504f

// global -> LDS direct copy, 16B per lane (dst = uniform base + lane*16).
__device__ __forceinline__ void gl16(const f16_t* g, f16_t* l) {
  __builtin_amdgcn_global_load_lds(
      (const __attribute__((address_space(1))) void*)g,
      (__attribute__((address_space(3))) void*)l, 16, 0, 0);
}

// ---------------------------------------------------------------------------
// Kernel 0: fused converts. Blocks 0-2047: hs fp32 -> fp16. Blocks 2048-2815:
// weights -> transposed [n][k] fp16 (rows: Wq^T 0-1023, Wk^T 1024-1535,
// Wv^T 1536-2047, Wo^T 2048-3071).
// ---------------------------------------------------------------------------
__global__ __launch_bounds__(256)
void convert_all(const float* __restrict__ hs,
                 const float* __restrict__ Wq, const float* __restrict__ Wk,
                 const float* __restrict__ Wv, const float* __restrict__ Wo,
                 f16_t* __restrict__ hf, f16_t* __restrict__ wtT)
{
  __shared__ float Tt[64][68];
  const int tid = threadIdx.x;

  if (blockIdx.x < 2048) {
    const size_t i = ((size_t)blockIdx.x * 256 + tid) * 8;
    float4 a = *(const float4*)&hs[i];
    float4 b = *(const float4*)&hs[i + 4];
    float xs[8] = {a.x, a.y, a.z, a.w, b.x, b.y, b.z, b.w};
    f16x8 v;
    #pragma unroll
    for (int j = 0; j < 8; ++j) v[j] = (f16_t)xs[j];
    *(f16x8*)&hf[i] = v;
    return;
  }

  const int wb = blockIdx.x - 2048;
  const int slot = wb >> 4, k0 = (wb & 15) * 64;

  const float* src; int N, ncol0, orow0;
  if (slot < 16)      { src = Wq; N = 1024; ncol0 = slot*64;      orow0 = slot*64; }
  else if (slot < 24) { src = Wk; N = 512;  ncol0 = (slot-16)*64; orow0 = 1024 + (slot-16)*64; }
  else if (slot < 32) { src = Wv; N = 512;  ncol0 = (slot-24)*64; orow0 = 1536 + (slot-24)*64; }
  else                { src = Wo; N = 1024; ncol0 = (slot-32)*64; orow0 = 2048 + (slot-32)*64; }

  const int tk = tid >> 6, tn = tid & 63;
  #pragma unroll
  for (int i = 0; i < 16; ++i)
    Tt[tn][tk*16 + i] = src[(size_t)(k0 + tk*16 + i) * N + ncol0 + tn];
  __syncthreads();

  const int n = tid >> 2, kc = (tid & 3) * 16;
  f16x8 a0, a1;
  #pragma unroll
  for (int i = 0; i < 8; ++i) {
    a0[i] = (f16_t)Tt[n][kc + i];
    a1[i] = (f16_t)Tt[n][kc + 8 + i];
  }
  const size_t ob = (size_t)(orow0 + n) * 1024 + k0 + kc;
  *(f16x8*)&wtT[ob]     = a0;
  *(f16x8*)&wtT[ob + 8] = a1;
}

// ---------------------------------------------------------------------------
// Kernel 1: QKV projection fp16 GEMM, WIDE SLOTS (128 cols = 2 heads/block).
// grid 512 XCD-swizzled = 32 row-tiles x 16 wide-slots (ws<8 Q, <12 K, else V).
// Per-head RMSNorm + RoPE epilogue; V stored kv-permuted for lane-local PV.
// ---------------------------------------------------------------------------
__global__ __launch_bounds__(256)
void qkv_kernel(const f16_t* __restrict__ hsf, const f16_t* __restrict__ wtT,
                const float* __restrict__ cosp, const float* __restrict__ sinp,
                const float* __restrict__ qnw, const float* __restrict__ knw,
                f16_t* __restrict__ q_o, f16_t* __restrict__ k_o,
                f16_t* __restrict__ vt_o)
{
  __shared__ __align__(16) f16_t Ah[128][64];  // 16 KB
  __shared__ __align__(16) f16_t Bh[128][64];  // 16 KB

  const int tid = threadIdx.x;
  const int lane = tid & 63, wave = tid >> 6;
  const int lo16 = lane & 15, hi4 = lane >> 4;
  const int lin = blockIdx.x;
  const int swz = (lin & 7) * 64 + (lin >> 3);   // 512 = 8 * 64, bijective
  const int m0 = (swz >> 4) * 128;
  const int ws = swz & 15;
  const int orow = ws * 128;

  int kind, hd0;
  if (ws < 8)       { kind = 0; hd0 = ws*2; }
  else if (ws < 12) { kind = 1; hd0 = (ws-8)*2; }
  else              { kind = 2; hd0 = (ws-12)*2; }

  f32x4 acc[2][8];
  #pragma unroll
  for (int qb = 0; qb < 2; ++qb)
    #pragma unroll
    for (int j = 0; j < 8; ++j) acc[qb][j] = f32x4{0.f, 0.f, 0.f, 0.f};

  const int ri = lane >> 3, pc = lane & 7;
  const int lcs = (pc ^ ri) * 8;   // pre-swizzled global chunk
  size_t aoff4[4]; f16_t* aldst4[4];
  size_t boff4[4]; f16_t* bldst4[4];
  #pragma unroll
  for (int q = 0; q < 4; ++q) {
    aoff4[q] = (size_t)(m0 + wave*32 + q*8 + ri) * PHID + lcs;
    aldst4[q] = &Ah[wave*32 + q*8][0];
    boff4[q] = (size_t)(orow + wave*32 + q*8 + ri) * 1024 + lcs;
    bldst4[q] = &Bh[wave*32 + q*8][0];
  }

  const int rsw = lo16 & 7;

  for (int k0 = 0; k0 < PHID; k0 += 64) {
    __syncthreads();
    #pragma unroll
    for (int q = 0; q < 4; ++q) gl16(hsf + aoff4[q] + k0, aldst4[q]);
    #pragma unroll
    for (int q = 0; q < 4; ++q) gl16(wtT + boff4[q] + k0, bldst4[q]);
    __syncthreads();

    #pragma unroll
    for (int t = 0; t < 2; ++t) {
      const int ccol = ((t*4 + hi4) ^ rsw) * 8;
      f16x8 ah[2];
      #pragma unroll
      for (int qb = 0; qb < 2; ++qb)
        ah[qb] = *(const f16x8*)&Ah[wave*32 + qb*16 + lo16][ccol];
      #pragma unroll
      for (int j = 0; j < 8; ++j) {
        f16x8 bh = *(const f16x8*)&Bh[j*16 + lo16][ccol];
        #pragma unroll
        for (int qb = 0; qb < 2; ++qb)
          acc[qb][j] = MFMAH(ah[qb], bh, acc[qb][j]);
      }
    }
  }

  // ---- epilogue: per-head RMSNorm + RoPE; fp16 stores ----
  float nwv[4];
  #pragma unroll
  for (int jj = 0; jj < 4; ++jj)
    nwv[jj] = (kind == 0) ? qnw[lo16 + 16*jj]
            : (kind == 1) ? knw[lo16 + 16*jj] : 1.0f;

  #pragma unroll
  for (int qb = 0; qb < 2; ++qb) {
    float sc[2][4];
    #pragma unroll
    for (int r = 0; r < 4; ++r) {
      float s0 = 0.f, s1 = 0.f;
      #pragma unroll
      for (int j = 0; j < 4; ++j) {
        s0 += acc[qb][j][r]   * acc[qb][j][r];
        s1 += acc[qb][j+4][r] * acc[qb][j+4][r];
      }
      #pragma unroll
      for (int m = 1; m < 16; m <<= 1) {
        s0 += __shfl_xor(s0, m);
        s1 += __shfl_xor(s1, m);
      }
      sc[0][r] = 1.0f / sqrtf(s0 * (1.0f/64.0f) + 1e-6f);
      sc[1][r] = 1.0f / sqrtf(s1 * (1.0f/64.0f) + 1e-6f);
    }

    float y[8][4];
    #pragma unroll
    for (int j = 0; j < 8; ++j)
      #pragma unroll
      for (int r = 0; r < 4; ++r)
        y[j][r] = acc[qb][j][r] * sc[j>>2][r] * nwv[j&3];

    if (kind == 2) {
      #pragma unroll
      for (int r = 0; r < 4; ++r) {
        int mg = m0 + wave*32 + qb*16 + hi4*4 + r;
        int b = mg >> 11, sq = mg & 2047;
        int g = sq & 63;
        int sp = (g & 3) | (((g >> 4) & 1) << 2) | (((g >> 2) & 1) << 3)
               | (((g >> 3) & 1) << 4) | (g & 32);
        int sq2 = (sq & ~63) | sp;
        #pragma unroll
        for (int j = 0; j < 8; ++j) {
          int d = lo16 + 16*(j & 3), hd = hd0 + (j >> 2);
          vt_o[((size_t)((b*PKV + hd)*PD + d))*PS + sq2] = (f16_t)y[j][r];
        }
      }
    } else {
      #pragma unroll
      for (int r = 0; r < 4; ++r) {
        int mg = m0 + wave*32 + qb*16 + hi4*4 + r;
        int b = mg >> 11, sq = mg & 2047;
        const float* cp = &cosp[(size_t)mg * PD];
        const float* sp = &sinp[(size_t)mg * PD];
        float z[8];
        #pragma unroll
        for (int j = 0; j < 8; ++j) {
          int d = lo16 + 16*(j & 3);
          float c = cp[d], s = sp[d];
          float rot = (j & 1) ? y[j-1][r] : -y[j+1][r];
          z[j] = y[j][r] * c + rot * s;
        }
        #pragma unroll
        for (int j = 0; j < 8; ++j) {
          int d = lo16 + 16*(j & 3), hd = hd0 + (j >> 2);
          if (kind == 0) {
            size_t idx = ((size_t)(b*PH + hd)*PS + sq)*PD + d;
            q_o[idx] = (f16_t)(z[j] * LOG2E);   // exp2-domain fold
          } else {
            size_t idx = ((size_t)(b*PKV + hd)*PS + sq)*PD + d;
            k_o[idx] = (f16_t)z[j];
          }
        }
      }
    }
  }
}

// ---------------------------------------------------------------------------
// Kernel 2: flash attention — r8 body + cvt_pkrtz packing + deferred lq
// reduction (cross-lane l-sum moved to epilogue; alpha is row-uniform so
// per-lane partials rescale correctly). gl16 double-buffered K/V
// (XOR-swizzled), lane-local P via pre-permuted V, exp2 softmax + defer-max,
// zero-C first MFMA. grid 1024 XCD-swizzled, 4 blocks/CU. LDS 32 KB.
// ---------------------------------------------------------------------------
__global__ __launch_bounds__(256, 4)
void attn_kernel(const f16_t* __restrict__ q_g, const f16_t* __restrict__ k_g,
                 const f16_t* __restrict__ vt_g,
                 f16_t* __restrict__ op, float2* __restrict__ ml)
{
  __shared__ __align__(16) char lds_raw[32768];
  f16_t (*Ks)[64][64] = (f16_t (*)[64][64])lds_raw;             // [2][64][64]
  f16_t (*Vs)[64][64] = (f16_t (*)[64][64])(lds_raw + 16384);   // [2][64][64]
  f16_t (*Ob)[72]     = (f16_t (*)[72])lds_raw;                 // epilogue overlay

  const int tid = threadIdx.x, lane = tid & 63, wave = tid >> 6;
  const int lo16 = lane & 15, hi4 = lane >> 4;
  const int lin = blockIdx.x;
  const int swz = (lin & 7) * 128 + (lin >> 3);
  const int qt = swz & 15;
  const int bh = (swz >> 4) & 31;
  const int ks = swz >> 9;
  const int b = bh >> 4, h = bh & 15, kvh = h >> 1;   // GQA groups=2

  f16x8 qf[2][2];
  #pragma unroll
  for (int qb = 0; qb < 2; ++qb) {
    const size_t qbase = ((size_t)(b*PH + h)*PS + qt*128 + wave*32 + qb*16 + lo16) * PD;
    #pragma unroll
    for (int t = 0; t < 2; ++t)
      qf[qb][t] = *(const f16x8*)&q_g[qbase + t*32 + hi4*8];
  }

  f32x4 o[2][4];
  float mq[2] = {-1e30f, -1e30f}, lq[2] = {0.f, 0.f};  // lq = per-lane partial
  #pragma unroll
  for (int qb = 0; qb < 2; ++qb)
    #pragma unroll
    for (int j = 0; j < 4; ++j) o[qb][j] = f32x4{0.f, 0.f, 0.f, 0.f};

  const f32x4 FZ = {0.f, 0.f, 0.f, 0.f};   // constant C for first MFMA

  const int ri = lane >> 3;
  const int lcs = ((lane & 7) ^ ri) * 8;   // pre-swizzled global chunk
  const size_t kbase = (size_t)(b*PKV + kvh) * PS * PD + (size_t)ks * 1024 * PD;
  const size_t vbase = (size_t)(b*PKV + kvh) * PD * PS + (size_t)ks * 1024;

  auto STAGE = [&](int kt, int buf) {
    const f16_t* kp = k_g + kbase + (size_t)kt * 64 * PD;
    const f16_t* vp = vt_g + vbase + kt * 64;
    #pragma unroll
    for (int i = 0; i < 2; ++i) {
      const int st = wave*2 + i;   // stripe of 8 rows
      gl16(kp + (st*8 + ri)*PD + lcs, &Ks[buf][st*8][0]);
      gl16(vp + (size_t)(st*8 + ri)*PS + lcs, &Vs[buf][st*8][0]);
    }
  };

  STAGE(0, 0);
  int cur = 0;
  const int rsw = lo16 & 7;

  for (int kt = 0; kt < 16; ++kt) {
    __syncthreads();   // buf[cur] ready; prev reads of buf[cur^1] done
    if (kt + 1 < 16) STAGE(kt + 1, cur ^ 1);

    // QK^T swapped: sacc[qb][j][r] = S'[kv = 16j + 4hi4 + r][q = 16qb + lo16]
    f32x4 sacc[2][4];
    __builtin_amdgcn_s_setprio(1);
    #pragma unroll
    for (int j = 0; j < 4; ++j) {
      f16x8 kf0 = *(const f16x8*)&Ks[cur][j*16 + lo16][(hi4 ^ rsw) * 8];
      f16x8 kf1 = *(const f16x8*)&Ks[cur][j*16 + lo16][((4 + hi4) ^ rsw) * 8];
      #pragma unroll
      for (int qb = 0; qb < 2; ++qb)
        sacc[qb][j] = MFMAH(kf1, qf[qb][1], MFMAH(kf0, qf[qb][0], FZ));
    }
    __builtin_amdgcn_s_setprio(0);

    // exp2-domain online softmax with defer-max (THR=8); fused exp + packed
    // cvt (cvt_pkrtz), per-lane partial l (cross-lane reduce deferred).
    f16x8 pa[2][2];
    #pragma unroll
    for (int qb = 0; qb < 2; ++qb) {
      float x0 = fmaxf(fmaxf(sacc[qb][0][0], sacc[qb][0][1]),
                       fmaxf(sacc[qb][0][2], sacc[qb][0][3]));
      float x1 = fmaxf(fmaxf(sacc[qb][1][0], sacc[qb][1][1]),
                       fmaxf(sacc[qb][1][2], sacc[qb][1][3]));
      float x2 = fmaxf(fmaxf(sacc[qb][2][0], sacc[qb][2][1]),
                       fmaxf(sacc[qb][2][2], sacc[qb][2][3]));
      float x3 = fmaxf(fmaxf(sacc[qb][3][0], sacc[qb][3][1]),
                       fmaxf(sacc[qb][3][2], sacc[qb][3][3]));
      float tm = fmaxf(fmaxf(x0, x1), fmaxf(x2, x3));
      tm = fmaxf(tm, __shfl_xor(tm, 16));
      tm = fmaxf(tm, __shfl_xor(tm, 32));
      if (!__all(tm <= mq[qb] + 8.0f)) {
        float mnew = fmaxf(mq[qb], tm);
        float alpha = __builtin_amdgcn_exp2f(mq[qb] - mnew);
        lq[qb] *= alpha;
        #pragma unroll
        for (int jd = 0; jd < 4; ++jd) o[qb][jd] *= alpha;
        mq[qb] = mnew;
      }
      float ls = 0.f;
      #pragma unroll
      for (int t = 0; t < 2; ++t) {
        union { fp16v2 h[4]; f16x8 v; } u;
        #pragma unroll
        for (int pr = 0; pr < 4; ++pr) {
          float p0 = __builtin_amdgcn_exp2f(sacc[qb][2*t + (pr>>1)][(pr&1)*2]     - mq[qb]);
          float p1 = __builtin_amdgcn_exp2f(sacc[qb][2*t + (pr>>1)][(pr&1)*2 + 1] - mq[qb]);
          ls += p0 + p1;
          u.h[pr] = __builtin_amdgcn_cvt_pkrtz(p0, p1);
        }
        pa[qb][t] = u.v;
      }
      lq[qb] += ls;   // per-lane partial; reduced once in epilogue
    }

    // PV: O^T = V^T(permuted) * P  (P fragments lane-local)
    __builtin_amdgcn_s_setprio(1);
    #pragma unroll
    for (int jd = 0; jd < 4; ++jd) {
      #pragma unroll
      for (int t = 0; t < 2; ++t) {
        f16x8 vf = *(const f16x8*)&Vs[cur][jd*16 + lo16][((t*4 + hi4) ^ rsw) * 8];
        #pragma unroll
        for (int qb = 0; qb < 2; ++qb)
          o[qb][jd] = MFMAH(vf, pa[qb][t], o[qb][jd]);
      }
    }
    __builtin_amdgcn_s_setprio(0);

    cur ^= 1;
  }

  // ---- epilogue: reduce lq across hi4 groups, then (m,l) + normalized O ----
  #pragma unroll
  for (int qb = 0; qb < 2; ++qb) {
    lq[qb] += __shfl_xor(lq[qb], 16);
    lq[qb] += __shfl_xor(lq[qb], 32);
  }
  __syncthreads();   // all waves done with K/V tiles; overlay is safe
  const int rbase = bh*PS + qt*128 + wave*32;
  if (hi4 == 0) {
    #pragma unroll
    for (int qb = 0; qb < 2; ++qb)
      ml[(size_t)ks*PR + rbase + qb*16 + lo16] = float2{mq[qb], lq[qb]};
  }
  #pragma unroll
  for (int qb = 0; qb < 2; ++qb) {
    float inv = 1.0f / lq[qb];
    #pragma unroll
    for (int jd = 0; jd < 4; ++jd)
      #pragma unroll
      for (int rp = 0; rp < 2; ++rp)
        *(f16x2*)&Ob[wave*32 + qb*16 + lo16][jd*16 + hi4*4 + 2*rp] =
            f16x2{(f16_t)(o[qb][jd][2*rp] * inv), (f16_t)(o[qb][jd][2*rp+1] * inv)};
  }
  {
    const int row = lane >> 1, half = lane & 1;
    const size_t gb_ = ((size_t)ks*PR + rbase + row) * PD + half*32;
    #pragma unroll
    for (int c = 0; c < 4; ++c)
      *(f16x8*)&op[gb_ + c*8] = *(const f16x8*)&Ob[wave*32 + row][half*32 + c*8];
  }
}

// ---------------------------------------------------------------------------
// Kernel 3: merge kv-split partials (normalized O + m,l in log2 domain).
// ---------------------------------------------------------------------------
__global__ __launch_bounds__(256)
void merge_kernel(const f16_t* __restrict__ op, const float2* __restrict__ ml,
                  f16_t* __restrict__ ao)
{
  const int gid = blockIdx.x * 256 + threadIdx.x;
  const int row = gid >> 3, oct = gid & 7;
  float2 e0 = ml[row], e1 = ml[PR + row];
  float M = fmaxf(e0.x, e1.x);
  float c0 = __builtin_amdgcn_exp2f(e0.x - M) * e0.y;
  float c1 = __builtin_amdgcn_exp2f(e1.x - M) * e1.y;
  float inv = 1.0f / (c0 + c1);
  c0 *= inv; c1 *= inv;
  f16x8 a = *(const f16x8*)&op[(size_t)row*PD + oct*8];
  f16x8 bq = *(const f16x8*)&op[(size_t)(PR + row)*PD + oct*8];
  f16x8 r;
  #pragma unroll
  for (int i = 0; i < 8; ++i)
    r[i] = (f16_t)(c0 * (float)a[i] + c1 * (float)bq[i]);
  const int bh = row >> 11, sq = row & 2047;
  const int b = bh >> 4, h = bh & 15;
  *(f16x8*)&ao[((size_t)(b*PS + sq))*PHID + h*PD + oct*8] = r;
}

// ---------------------------------------------------------------------------
// Kernel 4: out-projection, fp16 GEMM (ao x WoT) -> fp32. qkv-style staging:
// BK=64, gl16 with XOR swizzle. grid 512 XCD-swizzled. LDS 24 KB.
// ---------------------------------------------------------------------------
__global__ __launch_bounds__(256)
void oproj_kernel(const f16_t* __restrict__ ao, const f16_t* __restrict__ woT,
                  float* __restrict__ out)
{
  __shared__ __align__(16) f16_t As[128][64];  // 16 KB
  __shared__ __align__(16) f16_t Bs[64][64];   // 8 KB

  const int tid = threadIdx.x;
  const int lane = tid & 63, wave = tid >> 6;
  const int lo16 = lane & 15, hi4 = lane >> 4;
  const int lin = blockIdx.x;
  const int swz = (lin & 7) * 64 + (lin >> 3);
  const int m0 = (swz >> 4) * 128;
  const int col0 = (swz & 15) * 64;

  f32x4 acc[2][4];
  #pragma unroll
  for (int qb = 0; qb < 2; ++qb)
    #pragma unroll
    for (int j = 0; j < 4; ++j) acc[qb][j] = f32x4{0.f, 0.f, 0.f, 0.f};

  const int ri = lane >> 3, pc = lane & 7;
  const int lcs = (pc ^ ri) * 8;   // pre-swizzled global chunk
  size_t aoff4[4]; f16_t* aldst4[4];
  #pragma unroll
  for (int q = 0; q < 4; ++q) {
    aoff4[q] = (size_t)(m0 + wave*32 + q*8 + ri) * PHID + lcs;
    aldst4[q] = &As[wave*32 + q*8][0];
  }
  size_t boff[2]; int brow[2];
  #pragma unroll
  for (int q = 0; q < 2; ++q) {
    brow[q] = wave*16 + q*8;
    boff[q] = (size_t)(col0 + brow[q] + ri) * 1024 + lcs;
  }

  const int rsw = lo16 & 7;

  for (int k0 = 0; k0 < PHID; k0 += 64) {
    __syncthreads();
    #pragma unroll
    for (int q = 0; q < 4; ++q) gl16(ao + aoff4[q] + k0, aldst4[q]);
    #pragma unroll
    for (int q = 0; q < 2; ++q) gl16(woT + boff[q] + k0, &Bs[brow[q]][0]);
    __syncthreads();

    #pragma unroll
    for (int t = 0; t < 2; ++t) {
      const int ccol = ((t*4 + hi4) ^ rsw) * 8;
      f16x8 a[2];
      #pragma unroll
      for (int qb = 0; qb < 2; ++qb)
        a[qb] = *(const f16x8*)&As[wave*32 + qb*16 + lo16][ccol];
      #pragma unroll
      for (int j = 0; j < 4; ++j) {
        f16x8 bb = *(const f16x8*)&Bs[j*16 + lo16][ccol];
        #pragma unroll
        for (int qb = 0; qb < 2; ++qb)
          acc[qb][j] = MFMAH(a[qb], bb, acc[qb][j]);
      }
    }
  }

  #pragma unroll
  for (int qb = 0; qb < 2; ++qb)
    #pragma unroll
    for (int r = 0; r < 4; ++r) {
      int mg = m0 + wave*32 + qb*16 + hi4*4 + r;
      #pragma unroll
      for (int j = 0; j < 4; ++j)
        out[(size_t)mg*PHID + col0 + lo16 + 16*j] = acc[qb][j][r];
    }
}

// ---------------------------------------------------------------------------
extern "C" void kernel_launch(void* const* d_in, const int* in_sizes, int n_in,
                              void* d_out, int out_size, void* d_ws, size_t ws_size,
                              hipStream_t stream) {
  (void)in_sizes; (void)n_in; (void)out_size; (void)ws_size;
  const float* hs   = (const float*)d_in[0];
  const float* cosp = (const float*)d_in[1];
  const float* sinp = (const float*)d_in[2];
  // d_in[3] position_ids: only shape[-1]=2 used (NDIM=2 hardcoded)
  const float* Wq   = (const float*)d_in[4];
  const float* Wk   = (const float*)d_in[5];
  const float* Wv   = (const float*)d_in[6];
  const float* Wo   = (const float*)d_in[7];
  const float* qnw  = (const float*)d_in[8];
  const float* knw  = (const float*)d_in[9];
  float* out = (float*)d_out;

  const size_t QN = (size_t)PB*PH*PS*PD;    // 4,194,304 (== PR*PD == PM*PHID)
  const size_t KN = (size_t)PB*PKV*PS*PD;   // 2,097,152
  const size_t HN = (size_t)PM*PHID;        // 4,194,304
  char* wsb = (char*)d_ws;
  f16_t*  qv  = (f16_t*)wsb;                   // QN fp16 (8 MB)
  f16_t*  kv  = qv + QN;                       // KN (4 MB)
  f16_t*  vt  = kv + KN;                       // KN (4 MB)
  f16_t*  hsf = vt + KN;                       // HN (8 MB, dead after qkv)
  f16_t*  wtT = hsf + HN;                      // 3072*1024 (6 MB; rows 2048+ live)
  f16_t*  op  = wtT + (size_t)3072*1024;       // 2*QN (16 MB)
  float2* ml  = (float2*)(op + 2*QN);          // 2*PR float2 (1 MB)
  f16_t*  ao  = qv;   // alias: attn done with Q before merge (stream-ordered)
  const f16_t* woT = wtT + (size_t)2048*1024;

  convert_all<<<dim3(2816), 256, 0, stream>>>(hs, Wq, Wk, Wv, Wo, hsf, wtT);
  qkv_kernel<<<dim3(512),  256, 0, stream>>>(hsf, wtT, cosp, sinp,
                                             qnw, knw, qv, kv, vt);
  attn_kernel<<<dim3(1024), 256, 0, stream>>>(qv, kv, vt, op, ml);
  merge_kernel<<<dim3(PR*8/256), 256, 0, stream>>>(op, ml, ao);
  oproj_kernel<<<dim3(512), 256, 0, stream>>>(ao, woT, out);
}

// Round 15
// 113.810 us; speedup vs baseline: 1.2147x; 1.0180x over previous
//
#include <hip/hip_runtime.h>

// Problem constants
#define PB 2
#define PS 2048
#define PHID 1024
#define PH 16
#define PKV 8
#define PD 64
#define PM (PB*PS)    // 4096
#define PR (PB*PH*PS) // 65536 q-rows total

typedef _Float16 f16_t;
typedef _Float16 f16x8 __attribute__((ext_vector_type(8)));
typedef _Float16 f16x2 __attribute__((ext_vector_type(2)));
typedef __fp16 fp16v2 __attribute__((ext_vector_type(2)));   // cvt_pkrtz native type
typedef float f32x4 __attribute__((ext_vector_type(4)));

#define MFMAH(a,b,c)  __builtin_amdgcn_mfma_f32_16x16x32_f16((a),(b),(c),0,0,0)
#define LOG2E 1.44269504f

// global -> LDS direct copy, 16B per lane (dst = uniform base + lane*16).
__device__ __forceinline__ void gl16(const f16_t* g, f16_t* l) {
  __builtin_amdgcn_global_load_lds(
      (const __attribute__((address_space(1))) void*)g,
      (__attribute__((address_space(3))) void*)l, 16, 0, 0);
}

// ---------------------------------------------------------------------------
// Kernel 0: fused converts. Blocks 0-2047: hs fp32 -> fp16. Blocks 2048-2815:
// weights -> transposed [n][k] fp16 (rows: Wq^T 0-1023, Wk^T 1024-1535,
// Wv^T 1536-2047, Wo^T 2048-3071).
// ---------------------------------------------------------------------------
__global__ __launch_bounds__(256)
void convert_all(const float* __restrict__ hs,
                 const float* __restrict__ Wq, const float* __restrict__ Wk,
                 const float* __restrict__ Wv, const float* __restrict__ Wo,
                 f16_t* __restrict__ hf, f16_t* __restrict__ wtT)
{
  __shared__ float Tt[64][68];
  const int tid = threadIdx.x;

  if (blockIdx.x < 2048) {
    const size_t i = ((size_t)blockIdx.x * 256 + tid) * 8;
    float4 a = *(const float4*)&hs[i];
    float4 b = *(const float4*)&hs[i + 4];
    float xs[8] = {a.x, a.y, a.z, a.w, b.x, b.y, b.z, b.w};
    f16x8 v;
    #pragma unroll
    for (int j = 0; j < 8; ++j) v[j] = (f16_t)xs[j];
    *(f16x8*)&hf[i] = v;
    return;
  }

  const int wb = blockIdx.x - 2048;
  const int slot = wb >> 4, k0 = (wb & 15) * 64;

  const float* src; int N, ncol0, orow0;
  if (slot < 16)      { src = Wq; N = 1024; ncol0 = slot*64;      orow0 = slot*64; }
  else if (slot < 24) { src = Wk; N = 512;  ncol0 = (slot-16)*64; orow0 = 1024 + (slot-16)*64; }
  else if (slot < 32) { src = Wv; N = 512;  ncol0 = (slot-24)*64; orow0 = 1536 + (slot-24)*64; }
  else                { src = Wo; N = 1024; ncol0 = (slot-32)*64; orow0 = 2048 + (slot-32)*64; }

  const int tk = tid >> 6, tn = tid & 63;
  #pragma unroll
  for (int i = 0; i < 16; ++i)
    Tt[tn][tk*16 + i] = src[(size_t)(k0 + tk*16 + i) * N + ncol0 + tn];
  __syncthreads();

  const int n = tid >> 2, kc = (tid & 3) * 16;
  f16x8 a0, a1;
  #pragma unroll
  for (int i = 0; i < 8; ++i) {
    a0[i] = (f16_t)Tt[n][kc + i];
    a1[i] = (f16_t)Tt[n][kc + 8 + i];
  }
  const size_t ob = (size_t)(orow0 + n) * 1024 + k0 + kc;
  *(f16x8*)&wtT[ob]     = a0;
  *(f16x8*)&wtT[ob + 8] = a1;
}

// ---------------------------------------------------------------------------
// Kernel 1: QKV projection fp16 GEMM, WIDE SLOTS (128 cols = 2 heads/block).
// grid 512 XCD-swizzled = 32 row-tiles x 16 wide-slots (ws<8 Q, <12 K, else V).
// Per-head RMSNorm + RoPE epilogue; V stored kv-permuted for lane-local PV.
// ---------------------------------------------------------------------------
__global__ __launch_bounds__(256)
void qkv_kernel(const f16_t* __restrict__ hsf, const f16_t* __restrict__ wtT,
                const float* __restrict__ cosp, const float* __restrict__ sinp,
                const float* __restrict__ qnw, const float* __restrict__ knw,
                f16_t* __restrict__ q_o, f16_t* __restrict__ k_o,
                f16_t* __restrict__ vt_o)
{
  __shared__ __align__(16) f16_t Ah[128][64];  // 16 KB
  __shared__ __align__(16) f16_t Bh[128][64];  // 16 KB

  const int tid = threadIdx.x;
  const int lane = tid & 63, wave = tid >> 6;
  const int lo16 = lane & 15, hi4 = lane >> 4;
  const int lin = blockIdx.x;
  const int swz = (lin & 7) * 64 + (lin >> 3);   // 512 = 8 * 64, bijective
  const int m0 = (swz >> 4) * 128;
  const int ws = swz & 15;
  const int orow = ws * 128;

  int kind, hd0;
  if (ws < 8)       { kind = 0; hd0 = ws*2; }
  else if (ws < 12) { kind = 1; hd0 = (ws-8)*2; }
  else              { kind = 2; hd0 = (ws-12)*2; }

  f32x4 acc[2][8];
  #pragma unroll
  for (int qb = 0; qb < 2; ++qb)
    #pragma unroll
    for (int j = 0; j < 8; ++j) acc[qb][j] = f32x4{0.f, 0.f, 0.f, 0.f};

  const int ri = lane >> 3, pc = lane & 7;
  const int lcs = (pc ^ ri) * 8;   // pre-swizzled global chunk
  size_t aoff4[4]; f16_t* aldst4[4];
  size_t boff4[4]; f16_t* bldst4[4];
  #pragma unroll
  for (int q = 0; q < 4; ++q) {
    aoff4[q] = (size_t)(m0 + wave*32 + q*8 + ri) * PHID + lcs;
    aldst4[q] = &Ah[wave*32 + q*8][0];
    boff4[q] = (size_t)(orow + wave*32 + q*8 + ri) * 1024 + lcs;
    bldst4[q] = &Bh[wave*32 + q*8][0];
  }

  const int rsw = lo16 & 7;

  for (int k0 = 0; k0 < PHID; k0 += 64) {
    __syncthreads();
    #pragma unroll
    for (int q = 0; q < 4; ++q) gl16(hsf + aoff4[q] + k0, aldst4[q]);
    #pragma unroll
    for (int q = 0; q < 4; ++q) gl16(wtT + boff4[q] + k0, bldst4[q]);
    __syncthreads();

    #pragma unroll
    for (int t = 0; t < 2; ++t) {
      const int ccol = ((t*4 + hi4) ^ rsw) * 8;
      f16x8 ah[2];
      #pragma unroll
      for (int qb = 0; qb < 2; ++qb)
        ah[qb] = *(const f16x8*)&Ah[wave*32 + qb*16 + lo16][ccol];
      #pragma unroll
      for (int j = 0; j < 8; ++j) {
        f16x8 bh = *(const f16x8*)&Bh[j*16 + lo16][ccol];
        #pragma unroll
        for (int qb = 0; qb < 2; ++qb)
          acc[qb][j] = MFMAH(ah[qb], bh, acc[qb][j]);
      }
    }
  }

  // ---- epilogue: per-head RMSNorm + RoPE; fp16 stores ----
  float nwv[4];
  #pragma unroll
  for (int jj = 0; jj < 4; ++jj)
    nwv[jj] = (kind == 0) ? qnw[lo16 + 16*jj]
            : (kind == 1) ? knw[lo16 + 16*jj] : 1.0f;

  #pragma unroll
  for (int qb = 0; qb < 2; ++qb) {
    float sc[2][4];
    #pragma unroll
    for (int r = 0; r < 4; ++r) {
      float s0 = 0.f, s1 = 0.f;
      #pragma unroll
      for (int j = 0; j < 4; ++j) {
        s0 += acc[qb][j][r]   * acc[qb][j][r];
        s1 += acc[qb][j+4][r] * acc[qb][j+4][r];
      }
      #pragma unroll
      for (int m = 1; m < 16; m <<= 1) {
        s0 += __shfl_xor(s0, m);
        s1 += __shfl_xor(s1, m);
      }
      sc[0][r] = 1.0f / sqrtf(s0 * (1.0f/64.0f) + 1e-6f);
      sc[1][r] = 1.0f / sqrtf(s1 * (1.0f/64.0f) + 1e-6f);
    }

    float y[8][4];
    #pragma unroll
    for (int j = 0; j < 8; ++j)
      #pragma unroll
      for (int r = 0; r < 4; ++r)
        y[j][r] = acc[qb][j][r] * sc[j>>2][r] * nwv[j&3];

    if (kind == 2) {
      #pragma unroll
      for (int r = 0; r < 4; ++r) {
        int mg = m0 + wave*32 + qb*16 + hi4*4 + r;
        int b = mg >> 11, sq = mg & 2047;
        int g = sq & 63;
        int sp = (g & 3) | (((g >> 4) & 1) << 2) | (((g >> 2) & 1) << 3)
               | (((g >> 3) & 1) << 4) | (g & 32);
        int sq2 = (sq & ~63) | sp;
        #pragma unroll
        for (int j = 0; j < 8; ++j) {
          int d = lo16 + 16*(j & 3), hd = hd0 + (j >> 2);
          vt_o[((size_t)((b*PKV + hd)*PD + d))*PS + sq2] = (f16_t)y[j][r];
        }
      }
    } else {
      #pragma unroll
      for (int r = 0; r < 4; ++r) {
        int mg = m0 + wave*32 + qb*16 + hi4*4 + r;
        int b = mg >> 11, sq = mg & 2047;
        const float* cp = &cosp[(size_t)mg * PD];
        const float* sp = &sinp[(size_t)mg * PD];
        float z[8];
        #pragma unroll
        for (int j = 0; j < 8; ++j) {
          int d = lo16 + 16*(j & 3);
          float c = cp[d], s = sp[d];
          float rot = (j & 1) ? y[j-1][r] : -y[j+1][r];
          z[j] = y[j][r] * c + rot * s;
        }
        #pragma unroll
        for (int j = 0; j < 8; ++j) {
          int d = lo16 + 16*(j & 3), hd = hd0 + (j >> 2);
          if (kind == 0) {
            size_t idx = ((size_t)(b*PH + hd)*PS + sq)*PD + d;
            q_o[idx] = (f16_t)(z[j] * LOG2E);   // exp2-domain fold
          } else {
            size_t idx = ((size_t)(b*PKV + hd)*PS + sq)*PD + d;
            k_o[idx] = (f16_t)z[j];
          }
        }
      }
    }
  }
}

// ---------------------------------------------------------------------------
// Kernel 2: flash attention — 8-wave blocks (512 thr), 256 q-rows share each
// K/V tile (staging issues and K/V fetch halved). -mq folded into first
// MFMA's C operand (no subs in common path; wave-uniform branch duplicates
// the pack loop). gl16 double-buffered K/V (XOR-swizzled), lane-local P via
// pre-permuted V, exp2 softmax + defer-max, cvt_pkrtz pack, per-lane partial
// lq (epilogue reduce). grid 512 XCD-swizzled, 2 blocks/CU. LDS 32 KB.
// Epilogue O-bounce in 2 passes (Ob[128][72] overlay).
// ---------------------------------------------------------------------------
__global__ __launch_bounds__(512, 4)
void attn_kernel(const f16_t* __restrict__ q_g, const f16_t* __restrict__ k_g,
                 const f16_t* __restrict__ vt_g,
                 f16_t* __restrict__ op, float2* __restrict__ ml)
{
  __shared__ __align__(16) char lds_raw[32768];
  f16_t (*Ks)[64][64] = (f16_t (*)[64][64])lds_raw;             // [2][64][64]
  f16_t (*Vs)[64][64] = (f16_t (*)[64][64])(lds_raw + 16384);   // [2][64][64]
  f16_t (*Ob)[72]     = (f16_t (*)[72])lds_raw;                 // epilogue overlay (18.4 KB)

  const int tid = threadIdx.x, lane = tid & 63, wave = tid >> 6;  // wave 0..7
  const int lo16 = lane & 15, hi4 = lane >> 4;
  const int lin = blockIdx.x;
  const int swz = (lin & 7) * 64 + (lin >> 3);   // 512 = 8*64, bijective
  const int qt = swz & 7;
  const int bh = (swz >> 3) & 31;
  const int ks = swz >> 8;
  const int b = bh >> 4, h = bh & 15, kvh = h >> 1;   // GQA groups=2

  f16x8 qf[2][2];
  #pragma unroll
  for (int qb = 0; qb < 2; ++qb) {
    const size_t qbase = ((size_t)(b*PH + h)*PS + qt*256 + wave*32 + qb*16 + lo16) * PD;
    #pragma unroll
    for (int t = 0; t < 2; ++t)
      qf[qb][t] = *(const f16x8*)&q_g[qbase + t*32 + hi4*8];
  }

  f32x4 o[2][4];
  float mq[2] = {0.f, 0.f}, lq[2] = {0.f, 0.f};  // log2-domain max; per-lane l
  #pragma unroll
  for (int qb = 0; qb < 2; ++qb)
    #pragma unroll
    for (int j = 0; j < 4; ++j) o[qb][j] = f32x4{0.f, 0.f, 0.f, 0.f};

  const int ri = lane >> 3;
  const int lcs = ((lane & 7) ^ ri) * 8;   // pre-swizzled global chunk
  const size_t kbase = (size_t)(b*PKV + kvh) * PS * PD + (size_t)ks * 1024 * PD;
  const size_t vbase = (size_t)(b*PKV + kvh) * PD * PS + (size_t)ks * 1024;

  auto STAGE = [&](int kt, int buf) {
    const f16_t* kp = k_g + kbase + (size_t)kt * 64 * PD;
    const f16_t* vp = vt_g + vbase + kt * 64;
    const int st = wave;   // 8 waves cover the 8 stripes
    gl16(kp + (st*8 + ri)*PD + lcs, &Ks[buf][st*8][0]);
    gl16(vp + (size_t)(st*8 + ri)*PS + lcs, &Vs[buf][st*8][0]);
  };

  STAGE(0, 0);
  int cur = 0;
  const int rsw = lo16 & 7;

  for (int kt = 0; kt < 16; ++kt) {
    __syncthreads();   // buf[cur] ready; prev reads of buf[cur^1] done
    if (kt + 1 < 16) STAGE(kt + 1, cur ^ 1);

    // QK^T swapped, -mq folded into C: sacc = K.Q - mq (pre-shifted scores)
    f32x4 sacc[2][4];
    __builtin_amdgcn_s_setprio(1);
    #pragma unroll
    for (int j = 0; j < 4; ++j) {
      f16x8 kf0 = *(const f16x8*)&Ks[cur][j*16 + lo16][(hi4 ^ rsw) * 8];
      f16x8 kf1 = *(const f16x8*)&Ks[cur][j*16 + lo16][((4 + hi4) ^ rsw) * 8];
      #pragma unroll
      for (int qb = 0; qb < 2; ++qb) {
        const f32x4 mc = {-mq[qb], -mq[qb], -mq[qb], -mq[qb]};
        sacc[qb][j] = MFMAH(kf1, qf[qb][1], MFMAH(kf0, qf[qb][0], mc));
      }
    }
    __builtin_amdgcn_s_setprio(0);

    // exp2-domain softmax with defer-max (THR=8); fused exp + packed cvt.
    f16x8 pa[2][2];
    #pragma unroll
    for (int qb = 0; qb < 2; ++qb) {
      float x0 = fmaxf(fmaxf(sacc[qb][0][0], sacc[qb][0][1]),
                       fmaxf(sacc[qb][0][2], sacc[qb][0][3]));
      float x1 = fmaxf(fmaxf(sacc[qb][1][0], sacc[qb][1][1]),
                       fmaxf(sacc[qb][1][2], sacc[qb][1][3]));
      float x2 = fmaxf(fmaxf(sacc[qb][2][0], sacc[qb][2][1]),
                       fmaxf(sacc[qb][2][2], sacc[qb][2][3]));
      float x3 = fmaxf(fmaxf(sacc[qb][3][0], sacc[qb][3][1]),
                       fmaxf(sacc[qb][3][2], sacc[qb][3][3]));
      float tm = fmaxf(fmaxf(x0, x1), fmaxf(x2, x3));
      tm = fmaxf(tm, __shfl_xor(tm, 16));
      tm = fmaxf(tm, __shfl_xor(tm, 32));

      float ls = 0.f;
      if (!__all(tm <= 8.0f)) {
        // rescale path (rare after first tile)
        float tmx = fmaxf(tm, 0.f);
        float alpha = __builtin_amdgcn_exp2f(-tmx);
        lq[qb] *= alpha;
        #pragma unroll
        for (int jd = 0; jd < 4; ++jd) o[qb][jd] *= alpha;
        mq[qb] += tmx;
        #pragma unroll
        for (int t = 0; t < 2; ++t) {
          union { fp16v2 h[4]; f16x8 v; } u;
          #pragma unroll
          for (int pr = 0; pr < 4; ++pr) {
            float p0 = __builtin_amdgcn_exp2f(sacc[qb][2*t + (pr>>1)][(pr&1)*2]     - tmx);
            float p1 = __builtin_amdgcn_exp2f(sacc[qb][2*t + (pr>>1)][(pr&1)*2 + 1] - tmx);
            ls += p0 + p1;
            u.h[pr] = __builtin_amdgcn_cvt_pkrtz(p0, p1);
          }
          pa[qb][t] = u.v;
        }
      } else {
        // common path: no subtraction at all
        #pragma unroll
        for (int t = 0; t < 2; ++t) {
          union { fp16v2 h[4]; f16x8 v; } u;
          #pragma unroll
          for (int pr = 0; pr < 4; ++pr) {
            float p0 = __builtin_amdgcn_exp2f(sacc[qb][2*t + (pr>>1)][(pr&1)*2]);
            float p1 = __builtin_amdgcn_exp2f(sacc[qb][2*t + (pr>>1)][(pr&1)*2 + 1]);
            ls += p0 + p1;
            u.h[pr] = __builtin_amdgcn_cvt_pkrtz(p0, p1);
          }
          pa[qb][t] = u.v;
        }
      }
      lq[qb] += ls;   // per-lane partial; reduced once in epilogue
    }

    // PV: O^T = V^T(permuted) * P  (P fragments lane-local)
    __builtin_amdgcn_s_setprio(1);
    #pragma unroll
    for (int jd = 0; jd < 4; ++jd) {
      #pragma unroll
      for (int t = 0; t < 2; ++t) {
        f16x8 vf = *(const f16x8*)&Vs[cur][jd*16 + lo16][((t*4 + hi4) ^ rsw) * 8];
        #pragma unroll
        for (int qb = 0; qb < 2; ++qb)
          o[qb][jd] = MFMAH(vf, pa[qb][t], o[qb][jd]);
      }
    }
    __builtin_amdgcn_s_setprio(0);

    cur ^= 1;
  }

  // ---- epilogue: reduce lq, write (m,l), O-bounce in 2 passes ----
  #pragma unroll
  for (int qb = 0; qb < 2; ++qb) {
    lq[qb] += __shfl_xor(lq[qb], 16);
    lq[qb] += __shfl_xor(lq[qb], 32);
  }
  __syncthreads();   // all waves done with K/V tiles; overlay is safe
  const int rbase = bh*PS + qt*256 + wave*32;
  if (hi4 == 0) {
    #pragma unroll
    for (int qb = 0; qb < 2; ++qb)
      ml[(size_t)ks*PR + rbase + qb*16 + lo16] = float2{mq[qb], lq[qb]};
  }
  const int wl = wave & 3;
  #pragma unroll
  for (int pass = 0; pass < 2; ++pass) {
    if ((wave >> 2) == pass) {
      #pragma unroll
      for (int qb = 0; qb < 2; ++qb) {
        float inv = 1.0f / lq[qb];
        #pragma unroll
        for (int jd = 0; jd < 4; ++jd)
          #pragma unroll
          for (int rp = 0; rp < 2; ++rp)
            *(f16x2*)&Ob[wl*32 + qb*16 + lo16][jd*16 + hi4*4 + 2*rp] =
                f16x2{(f16_t)(o[qb][jd][2*rp] * inv), (f16_t)(o[qb][jd][2*rp+1] * inv)};
      }
      const int row = lane >> 1, half = lane & 1;
      const size_t gb_ = ((size_t)ks*PR + rbase + row) * PD + half*32;
      #pragma unroll
      for (int c = 0; c < 4; ++c)
        *(f16x8*)&op[gb_ + c*8] = *(const f16x8*)&Ob[wl*32 + row][half*32 + c*8];
    }
    __syncthreads();
  }
}

// ---------------------------------------------------------------------------
// Kernel 3: merge kv-split partials (normalized O + m,l in log2 domain).
// ---------------------------------------------------------------------------
__global__ __launch_bounds__(256)
void merge_kernel(const f16_t* __restrict__ op, const float2* __restrict__ ml,
                  f16_t* __restrict__ ao)
{
  const int gid = blockIdx.x * 256 + threadIdx.x;
  const int row = gid >> 3, oct = gid & 7;
  float2 e0 = ml[row], e1 = ml[PR + row];
  float M = fmaxf(e0.x, e1.x);
  float c0 = __builtin_amdgcn_exp2f(e0.x - M) * e0.y;
  float c1 = __builtin_amdgcn_exp2f(e1.x - M) * e1.y;
  float inv = 1.0f / (c0 + c1);
  c0 *= inv; c1 *= inv;
  f16x8 a = *(const f16x8*)&op[(size_t)row*PD + oct*8];
  f16x8 bq = *(const f16x8*)&op[(size_t)(PR + row)*PD + oct*8];
  f16x8 r;
  #pragma unroll
  for (int i = 0; i < 8; ++i)
    r[i] = (f16_t)(c0 * (float)a[i] + c1 * (float)bq[i]);
  const int bh = row >> 11, sq = row & 2047;
  const int b = bh >> 4, h = bh & 15;
  *(f16x8*)&ao[((size_t)(b*PS + sq))*PHID + h*PD + oct*8] = r;
}

// ---------------------------------------------------------------------------
// Kernel 4: out-projection, fp16 GEMM (ao x WoT) -> fp32. qkv-style staging:
// BK=64, gl16 with XOR swizzle. grid 512 XCD-swizzled. LDS 24 KB.
// ---------------------------------------------------------------------------
__global__ __launch_bounds__(256)
void oproj_kernel(const f16_t* __restrict__ ao, const f16_t* __restrict__ woT,
                  float* __restrict__ out)
{
  __shared__ __align__(16) f16_t As[128][64];  // 16 KB
  __shared__ __align__(16) f16_t Bs[64][64];   // 8 KB

  const int tid = threadIdx.x;
  const int lane = tid & 63, wave = tid >> 6;
  const int lo16 = lane & 15, hi4 = lane >> 4;
  const int lin = blockIdx.x;
  const int swz = (lin & 7) * 64 + (lin >> 3);
  const int m0 = (swz >> 4) * 128;
  const int col0 = (swz & 15) * 64;

  f32x4 acc[2][4];
  #pragma unroll
  for (int qb = 0; qb < 2; ++qb)
    #pragma unroll
    for (int j = 0; j < 4; ++j) acc[qb][j] = f32x4{0.f, 0.f, 0.f, 0.f};

  const int ri = lane >> 3, pc = lane & 7;
  const int lcs = (pc ^ ri) * 8;   // pre-swizzled global chunk
  size_t aoff4[4]; f16_t* aldst4[4];
  #pragma unroll
  for (int q = 0; q < 4; ++q) {
    aoff4[q] = (size_t)(m0 + wave*32 + q*8 + ri) * PHID + lcs;
    aldst4[q] = &As[wave*32 + q*8][0];
  }
  size_t boff[2]; int brow[2];
  #pragma unroll
  for (int q = 0; q < 2; ++q) {
    brow[q] = wave*16 + q*8;
    boff[q] = (size_t)(col0 + brow[q] + ri) * 1024 + lcs;
  }

  const int rsw = lo16 & 7;

  for (int k0 = 0; k0 < PHID; k0 += 64) {
    __syncthreads();
    #pragma unroll
    for (int q = 0; q < 4; ++q) gl16(ao + aoff4[q] + k0, aldst4[q]);
    #pragma unroll
    for (int q = 0; q < 2; ++q) gl16(woT + boff[q] + k0, &Bs[brow[q]][0]);
    __syncthreads();

    #pragma unroll
    for (int t = 0; t < 2; ++t) {
      const int ccol = ((t*4 + hi4) ^ rsw) * 8;
      f16x8 a[2];
      #pragma unroll
      for (int qb = 0; qb < 2; ++qb)
        a[qb] = *(const f16x8*)&As[wave*32 + qb*16 + lo16][ccol];
      #pragma unroll
      for (int j = 0; j < 4; ++j) {
        f16x8 bb = *(const f16x8*)&Bs[j*16 + lo16][ccol];
        #pragma unroll
        for (int qb = 0; qb < 2; ++qb)
          acc[qb][j] = MFMAH(a[qb], bb, acc[qb][j]);
      }
    }
  }

  #pragma unroll
  for (int qb = 0; qb < 2; ++qb)
    #pragma unroll
    for (int r = 0; r < 4; ++r) {
      int mg = m0 + wave*32 + qb*16 + hi4*4 + r;
      #pragma unroll
      for (int j = 0; j < 4; ++j)
        out[(size_t)mg*PHID + col0 + lo16 + 16*j] = acc[qb][j][r];
    }
}

// ---------------------------------------------------------------------------
extern "C" void kernel_launch(void* const* d_in, const int* in_sizes, int n_in,
                              void* d_out, int out_size, void* d_ws, size_t ws_size,
                              hipStream_t stream) {
  (void)in_sizes; (void)n_in; (void)out_size; (void)ws_size;
  const float* hs   = (const float*)d_in[0];
  const float* cosp = (const float*)d_in[1];
  const float* sinp = (const float*)d_in[2];
  // d_in[3] position_ids: only shape[-1]=2 used (NDIM=2 hardcoded)
  const float* Wq   = (const float*)d_in[4];
  const float* Wk   = (const float*)d_in[5];
  const float* Wv   = (const float*)d_in[6];
  const float* Wo   = (const float*)d_in[7];
  const float* qnw  = (const float*)d_in[8];
  const float* knw  = (const float*)d_in[9];
  float* out = (float*)d_out;

  const size_t QN = (size_t)PB*PH*PS*PD;    // 4,194,304 (== PR*PD == PM*PHID)
  const size_t KN = (size_t)PB*PKV*PS*PD;   // 2,097,152
  const size_t HN = (size_t)PM*PHID;        // 4,194,304
  char* wsb = (char*)d_ws;
  f16_t*  qv  = (f16_t*)wsb;                   // QN fp16 (8 MB)
  f16_t*  kv  = qv + QN;                       // KN (4 MB)
  f16_t*  vt  = kv + KN;                       // KN (4 MB)
  f16_t*  hsf = vt + KN;                       // HN (8 MB, dead after qkv)
  f16_t*  wtT = hsf + HN;                      // 3072*1024 (6 MB; rows 2048+ live)
  f16_t*  op  = wtT + (size_t)3072*1024;       // 2*QN (16 MB)
  float2* ml  = (float2*)(op + 2*QN);          // 2*PR float2 (1 MB)
  f16_t*  ao  = qv;   // alias: attn done with Q before merge (stream-ordered)
  const f16_t* woT = wtT + (size_t)2048*1024;

  convert_all<<<dim3(2816), 256, 0, stream>>>(hs, Wq, Wk, Wv, Wo, hsf, wtT);
  qkv_kernel<<<dim3(512),  256, 0, stream>>>(hsf, wtT, cosp, sinp,
                                             qnw, knw, qv, kv, vt);
  attn_kernel<<<dim3(512), 512, 0, stream>>>(qv, kv, vt, op, ml);
  merge_kernel<<<dim3(PR*8/256), 256, 0, stream>>>(op, ml, ao);
  oproj_kernel<<<dim3(512), 256, 0, stream>>>(ao, woT, out);
}